// Round 18
// baseline (538.356 us; speedup 1.0000x reference)
//
#include <hip/hip_runtime.h>
#include <cstdint>

#define CDIV(a, b) (((a) + (b) - 1) / (b))

typedef short bf16x8 __attribute__((ext_vector_type(8)));
typedef float f32x4 __attribute__((ext_vector_type(4)));

__device__ inline ushort f2bf_rn(float f) {
    uint32_t u = __float_as_uint(f);
    uint32_t rounding = 0x7FFF + ((u >> 16) & 1);
    return (ushort)((u + rounding) >> 16);
}
__device__ inline float bf2f(ushort h) { return __uint_as_float((uint32_t)h << 16); }

__device__ inline void wsplit_one(const float* __restrict__ W, int K, ushort* __restrict__ Whi,
                                  ushort* __restrict__ Wlo, int idx) {
    if (idx >= K * 256) return;
    int k = idx >> 8, n = idx & 255;
    float v = W[idx];
    ushort hi = f2bf_rn(v);
    ushort lo = f2bf_rn(v - bf2f(hi));
    int ks = k >> 5, r = k & 31;
    int lane = (r >> 3) * 16 + (n & 15);
    int j = r & 7;
    size_t d = (((size_t)ks * 16 + (n >> 4)) * 64 + lane) * 8 + j;
    Whi[d] = hi;
    Wlo[d] = lo;
}

// ---------------- fused prep: xsplit + 3x wsplit + zero(degc,sumbuf,maxbuf) ----------------
__global__ void k_prep(const float* __restrict__ x, int N, ushort* __restrict__ xhi,
                       const float* __restrict__ W1, ushort* __restrict__ W1hi,
                       ushort* __restrict__ W1lo, const float* __restrict__ W2,
                       ushort* __restrict__ W2hi, ushort* __restrict__ W2lo,
                       const float* __restrict__ W3, ushort* __restrict__ W3hi,
                       ushort* __restrict__ W3lo, int* __restrict__ degc,
                       float* __restrict__ sumbuf, int* __restrict__ maxbuf, int PB) {
    const int nx = CDIV(N * 128, 256);
    const int nz = CDIV(PB > N ? PB : N, 256);
    int b = blockIdx.x;
    int t = threadIdx.x;
    if (b < nx) {
        int i = b * 256 + t;
        if (i < N * 128) xhi[i] = f2bf_rn(x[i]);
        return;
    }
    b -= nx;
    if (b < 128) { wsplit_one(W1, 128, W1hi, W1lo, b * 256 + t); return; }
    b -= 128;
    if (b < 256) { wsplit_one(W2, 256, W2hi, W2lo, b * 256 + t); return; }
    b -= 256;
    if (b < 256) { wsplit_one(W3, 256, W3hi, W3lo, b * 256 + t); return; }
    b -= 256;
    if (b < nz) {
        int i = b * 256 + t;
        if (i < N) degc[i] = 0;
        if (i < PB) { sumbuf[i] = 0.f; maxbuf[i] = 0; }
    }
}

// ---------------- degree ----------------
__global__ void k_deg(const int* __restrict__ dst, int E, int* __restrict__ degc) {
    int e = blockIdx.x * blockDim.x + threadIdx.x;
    if (e < E) atomicAdd(&degc[dst[e]], 1);
}

// ---------------- scan -> row_ptr (+dis, +fill=0) ----------------
__global__ void k_scan_partial(const int* __restrict__ degc, int N, int* __restrict__ csum) {
    __shared__ int sm[256];
    int t = threadIdx.x;
    int idx = blockIdx.x * 1024 + t * 4;
    int s = 0;
#pragma unroll
    for (int j = 0; j < 4; ++j)
        if (idx + j < N) s += degc[idx + j];
    sm[t] = s;
    __syncthreads();
    for (int off = 128; off > 0; off >>= 1) {
        if (t < off) sm[t] += sm[t + off];
        __syncthreads();
    }
    if (t == 0) csum[blockIdx.x] = sm[0];
}

__global__ void k_scan_chunks(const int* __restrict__ csum, int nch, int* __restrict__ coff,
                              int* __restrict__ row_ptr, int N, int E) {
    if (threadIdx.x == 0 && blockIdx.x == 0) {
        int run = 0;
        for (int i = 0; i < nch; ++i) { coff[i] = run; run += csum[i]; }
        row_ptr[N] = E;
    }
}

__global__ void k_scan_final(const int* __restrict__ degc, int N, const int* __restrict__ coff,
                             int* __restrict__ row_ptr, int* __restrict__ fill,
                             float* __restrict__ dis) {
    __shared__ int sm[256];
    int t = threadIdx.x;
    int idx = blockIdx.x * 1024 + t * 4;
    int v[4];
    int s = 0;
#pragma unroll
    for (int j = 0; j < 4; ++j) {
        v[j] = (idx + j < N) ? degc[idx + j] : 0;
        s += v[j];
    }
    sm[t] = s;
    __syncthreads();
    for (int off = 1; off < 256; off <<= 1) {
        int x = (t >= off) ? sm[t - off] : 0;
        __syncthreads();
        sm[t] += x;
        __syncthreads();
    }
    int excl = sm[t] - s + coff[blockIdx.x];
#pragma unroll
    for (int j = 0; j < 4; ++j) {
        if (idx + j < N) {
            row_ptr[idx + j] = excl;
            fill[idx + j] = 0;
            dis[idx + j] = rsqrtf((float)v[j] + 1.0f);
            excl += v[j];
        }
    }
}

// ---------------- CSR fill ----------------
__global__ void k_fill(const int* __restrict__ src, const int* __restrict__ dst, int E,
                       const int* __restrict__ row_ptr, int* __restrict__ fill,
                       int* __restrict__ esrc) {
    int e = blockIdx.x * blockDim.x + threadIdx.x;
    if (e >= E) return;
    int d = dst[e], s = src[e];
    int pos = row_ptr[d] + atomicAdd(&fill[d], 1);
    esrc[pos] = s;
}

// ---------------- aggregation: row-major, one wave per node ----------------
template <int C, bool SELF_F32>
__global__ __launch_bounds__(256) void k_agg(const float* __restrict__ xf,
                                             const ushort* __restrict__ hhi,
                                             const float* __restrict__ dis,
                                             const int* __restrict__ row_ptr,
                                             const int* __restrict__ esrc, int N,
                                             ushort* __restrict__ ohi,
                                             ushort* __restrict__ olo) {
    constexpr int V = C / 64;
    int wave = (blockIdx.x * blockDim.x + threadIdx.x) >> 6;
    int lane = threadIdx.x & 63;
    if (wave >= N) return;
    const int i = wave;
    const float di = dis[i];
    const float dd = di * di;
    float acc[V];
    if constexpr (SELF_F32) {
        const float* xr = xf + (size_t)i * C + lane * V;
        if constexpr (V == 4) {
            float4 v = *reinterpret_cast<const float4*>(xr);
            acc[0] = dd * v.x; acc[1] = dd * v.y; acc[2] = dd * v.z; acc[3] = dd * v.w;
        } else {
            float2 v = *reinterpret_cast<const float2*>(xr);
            acc[0] = dd * v.x; acc[1] = dd * v.y;
        }
    } else {
        size_t sb = (size_t)i * C + lane * V;
        if constexpr (V == 4) {
            ushort4 h = *reinterpret_cast<const ushort4*>(hhi + sb);
            acc[0] = dd * bf2f(h.x); acc[1] = dd * bf2f(h.y);
            acc[2] = dd * bf2f(h.z); acc[3] = dd * bf2f(h.w);
        } else {
            ushort2 h = *reinterpret_cast<const ushort2*>(hhi + sb);
            acc[0] = dd * bf2f(h.x); acc[1] = dd * bf2f(h.y);
        }
    }
    const int p0 = row_ptr[i], p1 = row_ptr[i + 1];
    int p = p0;
    if constexpr (V == 4) {
        for (; p + 4 <= p1; p += 4) {
            int s0 = esrc[p], s1 = esrc[p + 1], s2 = esrc[p + 2], s3 = esrc[p + 3];
            float c0 = dis[s0] * di, c1 = dis[s1] * di, c2 = dis[s2] * di, c3 = dis[s3] * di;
            ushort4 v0 = *reinterpret_cast<const ushort4*>(hhi + (size_t)s0 * C + lane * V);
            ushort4 v1 = *reinterpret_cast<const ushort4*>(hhi + (size_t)s1 * C + lane * V);
            ushort4 v2 = *reinterpret_cast<const ushort4*>(hhi + (size_t)s2 * C + lane * V);
            ushort4 v3 = *reinterpret_cast<const ushort4*>(hhi + (size_t)s3 * C + lane * V);
            acc[0] += c0 * bf2f(v0.x); acc[1] += c0 * bf2f(v0.y);
            acc[2] += c0 * bf2f(v0.z); acc[3] += c0 * bf2f(v0.w);
            acc[0] += c1 * bf2f(v1.x); acc[1] += c1 * bf2f(v1.y);
            acc[2] += c1 * bf2f(v1.z); acc[3] += c1 * bf2f(v1.w);
            acc[0] += c2 * bf2f(v2.x); acc[1] += c2 * bf2f(v2.y);
            acc[2] += c2 * bf2f(v2.z); acc[3] += c2 * bf2f(v2.w);
            acc[0] += c3 * bf2f(v3.x); acc[1] += c3 * bf2f(v3.y);
            acc[2] += c3 * bf2f(v3.z); acc[3] += c3 * bf2f(v3.w);
        }
        for (; p < p1; ++p) {
            int s = esrc[p];
            float c = dis[s] * di;
            ushort4 v = *reinterpret_cast<const ushort4*>(hhi + (size_t)s * C + lane * V);
            acc[0] += c * bf2f(v.x); acc[1] += c * bf2f(v.y);
            acc[2] += c * bf2f(v.z); acc[3] += c * bf2f(v.w);
        }
    } else {
        for (; p + 4 <= p1; p += 4) {
            int s0 = esrc[p], s1 = esrc[p + 1], s2 = esrc[p + 2], s3 = esrc[p + 3];
            float c0 = dis[s0] * di, c1 = dis[s1] * di, c2 = dis[s2] * di, c3 = dis[s3] * di;
            ushort2 v0 = *reinterpret_cast<const ushort2*>(hhi + (size_t)s0 * C + lane * V);
            ushort2 v1 = *reinterpret_cast<const ushort2*>(hhi + (size_t)s1 * C + lane * V);
            ushort2 v2 = *reinterpret_cast<const ushort2*>(hhi + (size_t)s2 * C + lane * V);
            ushort2 v3 = *reinterpret_cast<const ushort2*>(hhi + (size_t)s3 * C + lane * V);
            acc[0] += c0 * bf2f(v0.x); acc[1] += c0 * bf2f(v0.y);
            acc[0] += c1 * bf2f(v1.x); acc[1] += c1 * bf2f(v1.y);
            acc[0] += c2 * bf2f(v2.x); acc[1] += c2 * bf2f(v2.y);
            acc[0] += c3 * bf2f(v3.x); acc[1] += c3 * bf2f(v3.y);
        }
        for (; p < p1; ++p) {
            int s = esrc[p];
            float c = dis[s] * di;
            ushort2 v = *reinterpret_cast<const ushort2*>(hhi + (size_t)s * C + lane * V);
            acc[0] += c * bf2f(v.x); acc[1] += c * bf2f(v.y);
        }
    }
    ushort hi[V], lo[V];
#pragma unroll
    for (int j = 0; j < V; ++j) {
        hi[j] = f2bf_rn(acc[j]);
        lo[j] = f2bf_rn(acc[j] - bf2f(hi[j]));
    }
    size_t ob = (size_t)i * C + lane * V;
    if constexpr (V == 4) {
        *reinterpret_cast<ushort4*>(ohi + ob) = make_ushort4(hi[0], hi[1], hi[2], hi[3]);
        *reinterpret_cast<ushort4*>(olo + ob) = make_ushort4(lo[0], lo[1], lo[2], lo[3]);
    } else {
        *reinterpret_cast<ushort2*>(ohi + ob) = make_ushort2(hi[0], hi[1]);
        *reinterpret_cast<ushort2*>(olo + ob) = make_ushort2(lo[0], lo[1]);
    }
}

// ---------------- barrier-free split-bf16 MFMA GEMM, BM=64 BN=256 ----------------
// BN=256: each A panel is read by exactly ONE block -> A traffic from L3 is
// 51 MB once (was 102-204 MB with BN=128/64 -> the measured ~50us floor).
// B streams from L2 (W panels 256 KB, L2-resident) with a depth-4 slot
// pipeline; A register-prefetched 2 k-steps. No LDS, no barriers.
template <int K, bool POOL>
__global__ __launch_bounds__(256) void k_gemm_bf16(const ushort* __restrict__ Ahi,
                                                   const ushort* __restrict__ Alo,
                                                   const ushort* __restrict__ Whi,
                                                   const ushort* __restrict__ Wlo,
                                                   const float* __restrict__ bias, int M,
                                                   ushort* __restrict__ Hhi,
                                                   const int* __restrict__ batch,
                                                   float* __restrict__ sumbuf,
                                                   int* __restrict__ maxbuf) {
    const int t = threadIdx.x;
    const int w = t >> 6, lane = t & 63;
    constexpr int KS = K / 32;
    constexpr int NSLOT = KS * 16;
    constexpr int DB = 4;

    const int bm = blockIdx.x * 64;
    const int rw = bm + w * 16;

    f32x4 acc[16] = {};

    int row0 = min(rw + (lane & 15), M - 1);
    const int kbase = (lane >> 4) * 8;
    const ushort* pa0h = Ahi + (size_t)row0 * K + kbase;
    const ushort* pa0l = Alo + (size_t)row0 * K + kbase;
    const size_t wlanep = (size_t)lane * 8;

    bf16x8 BH[NSLOT], BL[NSLOT];
    bf16x8 AH[KS], AL[KS];

    auto loadBslot = [&](int u) {
        const int ks = u >> 4, nf = u & 15;
        size_t widx = (((size_t)ks * 16 + nf) * 64) * 8 + wlanep;
        BH[u] = *reinterpret_cast<const bf16x8*>(Whi + widx);
        BL[u] = *reinterpret_cast<const bf16x8*>(Wlo + widx);
    };
    auto loadAset = [&](int ks) {
        AH[ks] = *reinterpret_cast<const bf16x8*>(pa0h + ks * 32);
        AL[ks] = *reinterpret_cast<const bf16x8*>(pa0l + ks * 32);
    };

#pragma unroll
    for (int u = 0; u < DB; ++u) loadBslot(u);
    loadAset(0);
    if (KS > 1) loadAset(1);

#pragma unroll
    for (int u = 0; u < NSLOT; ++u) {
        const int ks = u >> 4, nf = u & 15;
        if (u + DB < NSLOT) loadBslot(u + DB);
        if (nf == 0 && ks + 2 < KS) loadAset(ks + 2);
        acc[nf] = __builtin_amdgcn_mfma_f32_16x16x32_bf16(AH[ks], BH[u], acc[nf], 0, 0, 0);
        acc[nf] = __builtin_amdgcn_mfma_f32_16x16x32_bf16(AH[ks], BL[u], acc[nf], 0, 0, 0);
        acc[nf] = __builtin_amdgcn_mfma_f32_16x16x32_bf16(AL[ks], BH[u], acc[nf], 0, 0, 0);
    }

    const int colq = lane & 15;
    const int rowq = (lane >> 4) * 4;

    if constexpr (!POOL) {
#pragma unroll
        for (int nf = 0; nf < 16; ++nf) {
            int col = nf * 16 + colq;
            float bia = bias[col];
#pragma unroll
            for (int r2 = 0; r2 < 4; ++r2) {
                int rr = rw + rowq + r2;
                if (rr < M) {
                    float v = fmaxf(acc[nf][r2] + bia, 0.f);
                    Hhi[(size_t)rr * 256 + col] = f2bf_rn(v);
                }
            }
        }
    } else {
        int r0 = min(rw + rowq, M - 1);
        int r3 = min(rw + rowq + 3, M - 1);
        int g0 = batch[r0];
        int g3 = batch[r3];
        int gfirst = __shfl(g0, 0);
        bool uni = __all(g0 == gfirst && g3 == gfirst);
        if (uni) {
#pragma unroll
            for (int nf = 0; nf < 16; ++nf) {
                int col = nf * 16 + colq;
                float bia = bias[col];
                float s = 0.f, mx = 0.f;
#pragma unroll
                for (int r2 = 0; r2 < 4; ++r2) {
                    int rr = rw + rowq + r2;
                    float v = fmaxf(acc[nf][r2] + bia, 0.f);
                    if (rr < M) { s += v; mx = fmaxf(mx, v); }
                }
                s += __shfl_xor(s, 16);
                mx = fmaxf(mx, __shfl_xor(mx, 16));
                s += __shfl_xor(s, 32);
                mx = fmaxf(mx, __shfl_xor(mx, 32));
                if ((lane >> 4) == 0) {
                    atomicAdd(&sumbuf[gfirst * 256 + col], s);
                    atomicMax(&maxbuf[gfirst * 256 + col], __float_as_int(mx));
                }
            }
        } else {
#pragma unroll
            for (int nf = 0; nf < 16; ++nf) {
                int col = nf * 16 + colq;
                float bia = bias[col];
#pragma unroll
                for (int r2 = 0; r2 < 4; ++r2) {
                    int rr = rw + rowq + r2;
                    if (rr < M) {
                        float v = fmaxf(acc[nf][r2] + bia, 0.f);
                        int g = batch[rr];
                        atomicAdd(&sumbuf[g * 256 + col], v);
                        atomicMax(&maxbuf[g * 256 + col], __float_as_int(v));
                    }
                }
            }
        }
    }
}

// ---------------- fused pool-finalize + 3-layer MLP head ----------------
__global__ __launch_bounds__(512) void k_head(const float* __restrict__ sumbuf,
                                              const int* __restrict__ maxbuf,
                                              const int* __restrict__ batch, int N,
                                              const float* __restrict__ Wc1,
                                              const float* __restrict__ bc1,
                                              const float* __restrict__ Wc2,
                                              const float* __restrict__ bc2,
                                              const float* __restrict__ Wc3,
                                              const float* __restrict__ bc3,
                                              float* __restrict__ out) {
    __shared__ float gf[512];
    __shared__ float h1[512];
    __shared__ float h2[256];
    __shared__ int cntS;
    const int g = blockIdx.x;
    const int t = threadIdx.x;

    if (t == 0) {
        int lo = 0, hi = N;
        while (lo < hi) { int mid = (lo + hi) >> 1; if (batch[mid] < g) lo = mid + 1; else hi = mid; }
        int s = lo;
        lo = 0; hi = N;
        while (lo < hi) { int mid = (lo + hi) >> 1; if (batch[mid] < g + 1) lo = mid + 1; else hi = mid; }
        cntS = lo - s;
    }
    __syncthreads();
    const int cnt = cntS;
    if (t < 256) {
        float mean = sumbuf[g * 256 + t] / fmaxf((float)cnt, 1.0f);
        float mx = __int_as_float(maxbuf[g * 256 + t]);
        if (cnt == 0) { mean = 0.f; mx = 0.f; }
        gf[t] = mean;
        gf[256 + t] = mx;
    }
    __syncthreads();
    {
        float a0 = 0.f, a1 = 0.f, a2 = 0.f, a3 = 0.f;
        for (int k = 0; k < 512; k += 4) {
            a0 += gf[k + 0] * Wc1[(size_t)(k + 0) * 512 + t];
            a1 += gf[k + 1] * Wc1[(size_t)(k + 1) * 512 + t];
            a2 += gf[k + 2] * Wc1[(size_t)(k + 2) * 512 + t];
            a3 += gf[k + 3] * Wc1[(size_t)(k + 3) * 512 + t];
        }
        h1[t] = fmaxf((a0 + a1) + (a2 + a3) + bc1[t], 0.f);
    }
    __syncthreads();
    if (t < 256) {
        float a0 = 0.f, a1 = 0.f, a2 = 0.f, a3 = 0.f;
        for (int k = 0; k < 512; k += 4) {
            a0 += h1[k + 0] * Wc2[(size_t)(k + 0) * 256 + t];
            a1 += h1[k + 1] * Wc2[(size_t)(k + 1) * 256 + t];
            a2 += h1[k + 2] * Wc2[(size_t)(k + 2) * 256 + t];
            a3 += h1[k + 3] * Wc2[(size_t)(k + 3) * 256 + t];
        }
        h2[t] = fmaxf((a0 + a1) + (a2 + a3) + bc2[t], 0.f);
    }
    __syncthreads();
    if (t < 5) {
        float a = bc3[t];
        for (int k = 0; k < 256; ++k) a += h2[k] * Wc3[(size_t)k * 5 + t];
        out[(size_t)g * 5 + t] = a;
    }
}

extern "C" void kernel_launch(void* const* d_in, const int* in_sizes, int n_in, void* d_out,
                              int out_size, void* d_ws, size_t ws_size, hipStream_t stream) {
    const float* x = (const float*)d_in[0];
    const int* eidx = (const int*)d_in[1];
    const int* batch = (const int*)d_in[2];
    const float* W1 = (const float*)d_in[3];
    const float* b1 = (const float*)d_in[4];
    const float* W2 = (const float*)d_in[5];
    const float* b2 = (const float*)d_in[6];
    const float* W3 = (const float*)d_in[7];
    const float* b3 = (const float*)d_in[8];
    const float* Wc1 = (const float*)d_in[9];
    const float* bc1 = (const float*)d_in[10];
    const float* Wc2 = (const float*)d_in[11];
    const float* bc2 = (const float*)d_in[12];
    const float* Wc3 = (const float*)d_in[13];
    const float* bc3 = (const float*)d_in[14];
    float* out = (float*)d_out;

    const int N = in_sizes[2];
    const int E = in_sizes[1] / 2;
    const int G = out_size / 5;
    const int* src = eidx;
    const int* dst = eidx + E;

    char* p = (char*)d_ws;
    auto alloc = [&](size_t bytes) {
        void* r = (void*)p;
        p += (bytes + 255) & ~(size_t)255;
        return r;
    };
    float* dis = (float*)alloc((size_t)N * 4);
    int* degc = (int*)alloc((size_t)N * 4);
    int* row_ptr = (int*)alloc((size_t)(N + 1) * 4);
    int* fill = (int*)alloc((size_t)N * 4);
    const int nch = CDIV(N, 1024);
    int* csum = (int*)alloc((size_t)nch * 4);
    int* coff = (int*)alloc((size_t)nch * 4);
    int* esrc = (int*)alloc((size_t)E * 4);
    float* sumbuf = (float*)alloc((size_t)G * 256 * 4);
    int* maxbuf = (int*)alloc((size_t)G * 256 * 4);
    ushort* Ahi = (ushort*)alloc((size_t)N * 256 * 2);
    ushort* Alo = (ushort*)alloc((size_t)N * 256 * 2);
    ushort* Hhi = (ushort*)alloc((size_t)N * 256 * 2);
    ushort* Xhi = (ushort*)alloc((size_t)N * 128 * 2);
    ushort* W1hi = (ushort*)alloc((size_t)128 * 256 * 2);
    ushort* W1lo = (ushort*)alloc((size_t)128 * 256 * 2);
    ushort* W2hi = (ushort*)alloc((size_t)256 * 256 * 2);
    ushort* W2lo = (ushort*)alloc((size_t)256 * 256 * 2);
    ushort* W3hi = (ushort*)alloc((size_t)256 * 256 * 2);
    ushort* W3lo = (ushort*)alloc((size_t)256 * 256 * 2);
    (void)ws_size;

    // fused prep: xsplit + wsplit x3 + zero(degc,sumbuf,maxbuf)
    {
        const int PB = G * 256;
        const int nx = CDIV(N * 128, 256);
        const int nz = CDIV(PB > N ? PB : N, 256);
        const int nprep = nx + 128 + 256 + 256 + nz;
        k_prep<<<nprep, 256, 0, stream>>>(x, N, Xhi, W1, W1hi, W1lo, W2, W2hi, W2lo, W3, W3hi,
                                          W3lo, degc, sumbuf, maxbuf, PB);
    }

    k_deg<<<CDIV(E, 256), 256, 0, stream>>>(dst, E, degc);
    k_scan_partial<<<nch, 256, 0, stream>>>(degc, N, csum);
    k_scan_chunks<<<1, 64, 0, stream>>>(csum, nch, coff, row_ptr, N, E);
    k_scan_final<<<nch, 256, 0, stream>>>(degc, N, coff, row_ptr, fill, dis);
    k_fill<<<CDIV(E, 256), 256, 0, stream>>>(src, dst, E, row_ptr, fill, esrc);

    const int ggrid = CDIV(N, 64);

    // layer 1
    k_agg<128, true><<<CDIV(N * 64, 256), 256, 0, stream>>>(x, Xhi, dis, row_ptr, esrc, N,
                                                            Ahi, Alo);
    k_gemm_bf16<128, false><<<ggrid, 256, 0, stream>>>(Ahi, Alo, W1hi, W1lo, b1, N, Hhi,
                                                       batch, sumbuf, maxbuf);
    // layer 2
    k_agg<256, false><<<CDIV(N * 64, 256), 256, 0, stream>>>(nullptr, Hhi, dis, row_ptr,
                                                             esrc, N, Ahi, Alo);
    k_gemm_bf16<256, false><<<ggrid, 256, 0, stream>>>(Ahi, Alo, W2hi, W2lo, b2, N, Hhi,
                                                       batch, sumbuf, maxbuf);
    // layer 3 + fused pooling
    k_agg<256, false><<<CDIV(N * 64, 256), 256, 0, stream>>>(nullptr, Hhi, dis, row_ptr,
                                                             esrc, N, Ahi, Alo);
    k_gemm_bf16<256, true><<<ggrid, 256, 0, stream>>>(Ahi, Alo, W3hi, W3lo, b3, N, Hhi,
                                                      batch, sumbuf, maxbuf);

    // fused pool finalize + MLP head
    k_head<<<G, 512, 0, stream>>>(sumbuf, maxbuf, batch, N, Wc1, bc1, Wc2, bc2, Wc3, bc3, out);
}

// Round 19
// 407.106 us; speedup vs baseline: 1.3224x; 1.3224x over previous
//
#include <hip/hip_runtime.h>
#include <cstdint>

#define CDIV(a, b) (((a) + (b) - 1) / (b))

typedef short bf16x8 __attribute__((ext_vector_type(8)));
typedef float f32x4 __attribute__((ext_vector_type(4)));

__device__ inline ushort f2bf_rn(float f) {
    uint32_t u = __float_as_uint(f);
    uint32_t rounding = 0x7FFF + ((u >> 16) & 1);
    return (ushort)((u + rounding) >> 16);
}
__device__ inline float bf2f(ushort h) { return __uint_as_float((uint32_t)h << 16); }

__device__ inline void wsplit_one(const float* __restrict__ W, int K, ushort* __restrict__ Whi,
                                  ushort* __restrict__ Wlo, int idx) {
    if (idx >= K * 256) return;
    int k = idx >> 8, n = idx & 255;
    float v = W[idx];
    ushort hi = f2bf_rn(v);
    ushort lo = f2bf_rn(v - bf2f(hi));
    int ks = k >> 5, r = k & 31;
    int lane = (r >> 3) * 16 + (n & 15);
    int j = r & 7;
    size_t d = (((size_t)ks * 16 + (n >> 4)) * 64 + lane) * 8 + j;
    Whi[d] = hi;
    Wlo[d] = lo;
}

// ---------------- fused prep: xsplit + 3x wsplit + zero(degc,sumbuf,maxbuf) ----------------
__global__ void k_prep(const float* __restrict__ x, int N, ushort* __restrict__ xhi,
                       const float* __restrict__ W1, ushort* __restrict__ W1hi,
                       ushort* __restrict__ W1lo, const float* __restrict__ W2,
                       ushort* __restrict__ W2hi, ushort* __restrict__ W2lo,
                       const float* __restrict__ W3, ushort* __restrict__ W3hi,
                       ushort* __restrict__ W3lo, int* __restrict__ degc,
                       float* __restrict__ sumbuf, int* __restrict__ maxbuf, int PB) {
    const int nx = CDIV(N * 128, 256);
    const int nz = CDIV(PB > N ? PB : N, 256);
    int b = blockIdx.x;
    int t = threadIdx.x;
    if (b < nx) {
        int i = b * 256 + t;
        if (i < N * 128) xhi[i] = f2bf_rn(x[i]);
        return;
    }
    b -= nx;
    if (b < 128) { wsplit_one(W1, 128, W1hi, W1lo, b * 256 + t); return; }
    b -= 128;
    if (b < 256) { wsplit_one(W2, 256, W2hi, W2lo, b * 256 + t); return; }
    b -= 256;
    if (b < 256) { wsplit_one(W3, 256, W3hi, W3lo, b * 256 + t); return; }
    b -= 256;
    if (b < nz) {
        int i = b * 256 + t;
        if (i < N) degc[i] = 0;
        if (i < PB) { sumbuf[i] = 0.f; maxbuf[i] = 0; }
    }
}

// ---------------- degree ----------------
__global__ void k_deg(const int* __restrict__ dst, int E, int* __restrict__ degc) {
    int e = blockIdx.x * blockDim.x + threadIdx.x;
    if (e < E) atomicAdd(&degc[dst[e]], 1);
}

// ---------------- scan -> row_ptr (+dis, +fill=0) ----------------
__global__ void k_scan_partial(const int* __restrict__ degc, int N, int* __restrict__ csum) {
    __shared__ int sm[256];
    int t = threadIdx.x;
    int idx = blockIdx.x * 1024 + t * 4;
    int s = 0;
#pragma unroll
    for (int j = 0; j < 4; ++j)
        if (idx + j < N) s += degc[idx + j];
    sm[t] = s;
    __syncthreads();
    for (int off = 128; off > 0; off >>= 1) {
        if (t < off) sm[t] += sm[t + off];
        __syncthreads();
    }
    if (t == 0) csum[blockIdx.x] = sm[0];
}

__global__ void k_scan_chunks(const int* __restrict__ csum, int nch, int* __restrict__ coff,
                              int* __restrict__ row_ptr, int N, int E) {
    if (threadIdx.x == 0 && blockIdx.x == 0) {
        int run = 0;
        for (int i = 0; i < nch; ++i) { coff[i] = run; run += csum[i]; }
        row_ptr[N] = E;
    }
}

__global__ void k_scan_final(const int* __restrict__ degc, int N, const int* __restrict__ coff,
                             int* __restrict__ row_ptr, int* __restrict__ fill,
                             float* __restrict__ dis) {
    __shared__ int sm[256];
    int t = threadIdx.x;
    int idx = blockIdx.x * 1024 + t * 4;
    int v[4];
    int s = 0;
#pragma unroll
    for (int j = 0; j < 4; ++j) {
        v[j] = (idx + j < N) ? degc[idx + j] : 0;
        s += v[j];
    }
    sm[t] = s;
    __syncthreads();
    for (int off = 1; off < 256; off <<= 1) {
        int x = (t >= off) ? sm[t - off] : 0;
        __syncthreads();
        sm[t] += x;
        __syncthreads();
    }
    int excl = sm[t] - s + coff[blockIdx.x];
#pragma unroll
    for (int j = 0; j < 4; ++j) {
        if (idx + j < N) {
            row_ptr[idx + j] = excl;
            fill[idx + j] = 0;
            dis[idx + j] = rsqrtf((float)v[j] + 1.0f);
            excl += v[j];
        }
    }
}

// ---------------- CSR fill ----------------
__global__ void k_fill(const int* __restrict__ src, const int* __restrict__ dst, int E,
                       const int* __restrict__ row_ptr, int* __restrict__ fill,
                       int* __restrict__ esrc) {
    int e = blockIdx.x * blockDim.x + threadIdx.x;
    if (e >= E) return;
    int d = dst[e], s = src[e];
    int pos = row_ptr[d] + atomicAdd(&fill[d], 1);
    esrc[pos] = s;
}

// ---------------- aggregation: row-major, one wave per node ----------------
template <int C, bool SELF_F32>
__global__ __launch_bounds__(256) void k_agg(const float* __restrict__ xf,
                                             const ushort* __restrict__ hhi,
                                             const float* __restrict__ dis,
                                             const int* __restrict__ row_ptr,
                                             const int* __restrict__ esrc, int N,
                                             ushort* __restrict__ ohi,
                                             ushort* __restrict__ olo) {
    constexpr int V = C / 64;
    int wave = (blockIdx.x * blockDim.x + threadIdx.x) >> 6;
    int lane = threadIdx.x & 63;
    if (wave >= N) return;
    const int i = wave;
    const float di = dis[i];
    const float dd = di * di;
    float acc[V];
    if constexpr (SELF_F32) {
        const float* xr = xf + (size_t)i * C + lane * V;
        if constexpr (V == 4) {
            float4 v = *reinterpret_cast<const float4*>(xr);
            acc[0] = dd * v.x; acc[1] = dd * v.y; acc[2] = dd * v.z; acc[3] = dd * v.w;
        } else {
            float2 v = *reinterpret_cast<const float2*>(xr);
            acc[0] = dd * v.x; acc[1] = dd * v.y;
        }
    } else {
        size_t sb = (size_t)i * C + lane * V;
        if constexpr (V == 4) {
            ushort4 h = *reinterpret_cast<const ushort4*>(hhi + sb);
            acc[0] = dd * bf2f(h.x); acc[1] = dd * bf2f(h.y);
            acc[2] = dd * bf2f(h.z); acc[3] = dd * bf2f(h.w);
        } else {
            ushort2 h = *reinterpret_cast<const ushort2*>(hhi + sb);
            acc[0] = dd * bf2f(h.x); acc[1] = dd * bf2f(h.y);
        }
    }
    const int p0 = row_ptr[i], p1 = row_ptr[i + 1];
    int p = p0;
    if constexpr (V == 4) {
        for (; p + 4 <= p1; p += 4) {
            int s0 = esrc[p], s1 = esrc[p + 1], s2 = esrc[p + 2], s3 = esrc[p + 3];
            float c0 = dis[s0] * di, c1 = dis[s1] * di, c2 = dis[s2] * di, c3 = dis[s3] * di;
            ushort4 v0 = *reinterpret_cast<const ushort4*>(hhi + (size_t)s0 * C + lane * V);
            ushort4 v1 = *reinterpret_cast<const ushort4*>(hhi + (size_t)s1 * C + lane * V);
            ushort4 v2 = *reinterpret_cast<const ushort4*>(hhi + (size_t)s2 * C + lane * V);
            ushort4 v3 = *reinterpret_cast<const ushort4*>(hhi + (size_t)s3 * C + lane * V);
            acc[0] += c0 * bf2f(v0.x); acc[1] += c0 * bf2f(v0.y);
            acc[2] += c0 * bf2f(v0.z); acc[3] += c0 * bf2f(v0.w);
            acc[0] += c1 * bf2f(v1.x); acc[1] += c1 * bf2f(v1.y);
            acc[2] += c1 * bf2f(v1.z); acc[3] += c1 * bf2f(v1.w);
            acc[0] += c2 * bf2f(v2.x); acc[1] += c2 * bf2f(v2.y);
            acc[2] += c2 * bf2f(v2.z); acc[3] += c2 * bf2f(v2.w);
            acc[0] += c3 * bf2f(v3.x); acc[1] += c3 * bf2f(v3.y);
            acc[2] += c3 * bf2f(v3.z); acc[3] += c3 * bf2f(v3.w);
        }
        for (; p < p1; ++p) {
            int s = esrc[p];
            float c = dis[s] * di;
            ushort4 v = *reinterpret_cast<const ushort4*>(hhi + (size_t)s * C + lane * V);
            acc[0] += c * bf2f(v.x); acc[1] += c * bf2f(v.y);
            acc[2] += c * bf2f(v.z); acc[3] += c * bf2f(v.w);
        }
    } else {
        for (; p + 4 <= p1; p += 4) {
            int s0 = esrc[p], s1 = esrc[p + 1], s2 = esrc[p + 2], s3 = esrc[p + 3];
            float c0 = dis[s0] * di, c1 = dis[s1] * di, c2 = dis[s2] * di, c3 = dis[s3] * di;
            ushort2 v0 = *reinterpret_cast<const ushort2*>(hhi + (size_t)s0 * C + lane * V);
            ushort2 v1 = *reinterpret_cast<const ushort2*>(hhi + (size_t)s1 * C + lane * V);
            ushort2 v2 = *reinterpret_cast<const ushort2*>(hhi + (size_t)s2 * C + lane * V);
            ushort2 v3 = *reinterpret_cast<const ushort2*>(hhi + (size_t)s3 * C + lane * V);
            acc[0] += c0 * bf2f(v0.x); acc[1] += c0 * bf2f(v0.y);
            acc[0] += c1 * bf2f(v1.x); acc[1] += c1 * bf2f(v1.y);
            acc[0] += c2 * bf2f(v2.x); acc[1] += c2 * bf2f(v2.y);
            acc[0] += c3 * bf2f(v3.x); acc[1] += c3 * bf2f(v3.y);
        }
        for (; p < p1; ++p) {
            int s = esrc[p];
            float c = dis[s] * di;
            ushort2 v = *reinterpret_cast<const ushort2*>(hhi + (size_t)s * C + lane * V);
            acc[0] += c * bf2f(v.x); acc[1] += c * bf2f(v.y);
        }
    }
    ushort hi[V], lo[V];
#pragma unroll
    for (int j = 0; j < V; ++j) {
        hi[j] = f2bf_rn(acc[j]);
        lo[j] = f2bf_rn(acc[j] - bf2f(hi[j]));
    }
    size_t ob = (size_t)i * C + lane * V;
    if constexpr (V == 4) {
        *reinterpret_cast<ushort4*>(ohi + ob) = make_ushort4(hi[0], hi[1], hi[2], hi[3]);
        *reinterpret_cast<ushort4*>(olo + ob) = make_ushort4(lo[0], lo[1], lo[2], lo[3]);
    } else {
        *reinterpret_cast<ushort2*>(ohi + ob) = make_ushort2(hi[0], hi[1]);
        *reinterpret_cast<ushort2*>(olo + ob) = make_ushort2(lo[0], lo[1]);
    }
}

// ---------------- pipelined split-bf16 MFMA GEMM, BM=64 BN=128 (R16 best) ----------------
template <int K, bool POOL>
__global__ __launch_bounds__(256) void k_gemm_bf16(const ushort* __restrict__ Ahi,
                                                   const ushort* __restrict__ Alo,
                                                   const ushort* __restrict__ Whi,
                                                   const ushort* __restrict__ Wlo,
                                                   const float* __restrict__ bias, int M,
                                                   ushort* __restrict__ Hhi,
                                                   const int* __restrict__ batch,
                                                   float* __restrict__ sumbuf,
                                                   int* __restrict__ maxbuf) {
    __shared__ ushort Bs[2][2][8][512];  // 32 KB
    const int t = threadIdx.x;
    const int w = t >> 6, lane = t & 63;
    constexpr int KS = K / 32;

    // bijective XCD-chunked swizzle (m204)
    const int nwg = (int)gridDim.x;
    const int orig = (int)blockIdx.x;
    const int q = nwg >> 3, r = nwg & 7;
    const int xcd = orig & 7;
    const int swz = (xcd < r ? xcd * (q + 1) : r * (q + 1) + (xcd - r) * q) + (orig >> 3);
    const int bm = (swz >> 1) * 64;
    const int bn = (swz & 1) * 128;
    const int rw = bm + w * 16;

    f32x4 acc[8] = {};

    int row0 = min(rw + (lane & 15), M - 1);
    const int kbase = (lane >> 4) * 8;
    const ushort* pa0h = Ahi + (size_t)row0 * K + kbase;
    const ushort* pa0l = Alo + (size_t)row0 * K + kbase;
    const int nf0 = bn >> 4;

    bf16x8 sbh[2], sbl[2];
    auto loadB = [&](int ks) {
#pragma unroll
        for (int q2 = 0; q2 < 2; ++q2) {
            int nf = (w << 1) | q2;
            size_t widx = (((size_t)ks * 16 + nf0 + nf) * 64 + lane) * 8;
            sbh[q2] = *reinterpret_cast<const bf16x8*>(Whi + widx);
            sbl[q2] = *reinterpret_cast<const bf16x8*>(Wlo + widx);
        }
    };
    auto writeB = [&](int b) {
#pragma unroll
        for (int q2 = 0; q2 < 2; ++q2) {
            int nf = (w << 1) | q2;
            *reinterpret_cast<bf16x8*>(&Bs[b][0][nf][lane * 8]) = sbh[q2];
            *reinterpret_cast<bf16x8*>(&Bs[b][1][nf][lane * 8]) = sbl[q2];
        }
    };

    bf16x8 c0h, c0l, n0h, n0l, m0h, m0l;
    auto loadA = [&](int ks, bf16x8& xh, bf16x8& xl) {
        xh = *reinterpret_cast<const bf16x8*>(pa0h + ks * 32);
        xl = *reinterpret_cast<const bf16x8*>(pa0l + ks * 32);
    };

    loadB(0);
    writeB(0);
    loadA(0, c0h, c0l);
    if (KS > 1) loadA(1, n0h, n0l);
    if (KS > 1) loadB(1);
    __syncthreads();

#pragma unroll
    for (int ks = 0; ks < KS; ++ks) {
        const int buf = ks & 1;
        if (ks + 2 < KS) loadA(ks + 2, m0h, m0l);
#pragma unroll
        for (int nf = 0; nf < 8; ++nf) {
            bf16x8 bh = *reinterpret_cast<const bf16x8*>(&Bs[buf][0][nf][lane * 8]);
            bf16x8 bl = *reinterpret_cast<const bf16x8*>(&Bs[buf][1][nf][lane * 8]);
            acc[nf] = __builtin_amdgcn_mfma_f32_16x16x32_bf16(c0h, bh, acc[nf], 0, 0, 0);
            acc[nf] = __builtin_amdgcn_mfma_f32_16x16x32_bf16(c0h, bl, acc[nf], 0, 0, 0);
            acc[nf] = __builtin_amdgcn_mfma_f32_16x16x32_bf16(c0l, bh, acc[nf], 0, 0, 0);
        }
        if (ks + 1 < KS) {
            writeB(buf ^ 1);
            if (ks + 2 < KS) loadB(ks + 2);
            __syncthreads();
            c0h = n0h; c0l = n0l;
            n0h = m0h; n0l = m0l;
        }
    }

    const int colq = lane & 15;
    const int rowq = (lane >> 4) * 4;

    if constexpr (!POOL) {
#pragma unroll
        for (int nf = 0; nf < 8; ++nf) {
            int col = bn + nf * 16 + colq;
            float bia = bias[col];
#pragma unroll
            for (int r2 = 0; r2 < 4; ++r2) {
                int rr = rw + rowq + r2;
                if (rr < M) {
                    float v = fmaxf(acc[nf][r2] + bia, 0.f);
                    Hhi[(size_t)rr * 256 + col] = f2bf_rn(v);
                }
            }
        }
    } else {
        int r0 = min(rw + rowq, M - 1);
        int r3 = min(rw + rowq + 3, M - 1);
        int g0 = batch[r0];
        int g3 = batch[r3];
        int gfirst = __shfl(g0, 0);
        bool uni = __all(g0 == gfirst && g3 == gfirst);
        if (uni) {
#pragma unroll
            for (int nf = 0; nf < 8; ++nf) {
                int col = bn + nf * 16 + colq;
                float bia = bias[col];
                float s = 0.f, mx = 0.f;
#pragma unroll
                for (int r2 = 0; r2 < 4; ++r2) {
                    int rr = rw + rowq + r2;
                    float v = fmaxf(acc[nf][r2] + bia, 0.f);
                    if (rr < M) { s += v; mx = fmaxf(mx, v); }
                }
                s += __shfl_xor(s, 16);
                mx = fmaxf(mx, __shfl_xor(mx, 16));
                s += __shfl_xor(s, 32);
                mx = fmaxf(mx, __shfl_xor(mx, 32));
                if ((lane >> 4) == 0) {
                    atomicAdd(&sumbuf[gfirst * 256 + col], s);
                    atomicMax(&maxbuf[gfirst * 256 + col], __float_as_int(mx));
                }
            }
        } else {
#pragma unroll
            for (int nf = 0; nf < 8; ++nf) {
                int col = bn + nf * 16 + colq;
                float bia = bias[col];
#pragma unroll
                for (int r2 = 0; r2 < 4; ++r2) {
                    int rr = rw + rowq + r2;
                    if (rr < M) {
                        float v = fmaxf(acc[nf][r2] + bia, 0.f);
                        int g = batch[rr];
                        atomicAdd(&sumbuf[g * 256 + col], v);
                        atomicMax(&maxbuf[g * 256 + col], __float_as_int(v));
                    }
                }
            }
        }
    }
}

// ---------------- fused pool-finalize + 3-layer MLP head ----------------
__global__ __launch_bounds__(512) void k_head(const float* __restrict__ sumbuf,
                                              const int* __restrict__ maxbuf,
                                              const int* __restrict__ batch, int N,
                                              const float* __restrict__ Wc1,
                                              const float* __restrict__ bc1,
                                              const float* __restrict__ Wc2,
                                              const float* __restrict__ bc2,
                                              const float* __restrict__ Wc3,
                                              const float* __restrict__ bc3,
                                              float* __restrict__ out) {
    __shared__ float gf[512];
    __shared__ float h1[512];
    __shared__ float h2[256];
    __shared__ int cntS;
    const int g = blockIdx.x;
    const int t = threadIdx.x;

    if (t == 0) {
        int lo = 0, hi = N;
        while (lo < hi) { int mid = (lo + hi) >> 1; if (batch[mid] < g) lo = mid + 1; else hi = mid; }
        int s = lo;
        lo = 0; hi = N;
        while (lo < hi) { int mid = (lo + hi) >> 1; if (batch[mid] < g + 1) lo = mid + 1; else hi = mid; }
        cntS = lo - s;
    }
    __syncthreads();
    const int cnt = cntS;
    if (t < 256) {
        float mean = sumbuf[g * 256 + t] / fmaxf((float)cnt, 1.0f);
        float mx = __int_as_float(maxbuf[g * 256 + t]);
        if (cnt == 0) { mean = 0.f; mx = 0.f; }
        gf[t] = mean;
        gf[256 + t] = mx;
    }
    __syncthreads();
    {
        float a0 = 0.f, a1 = 0.f, a2 = 0.f, a3 = 0.f;
        for (int k = 0; k < 512; k += 4) {
            a0 += gf[k + 0] * Wc1[(size_t)(k + 0) * 512 + t];
            a1 += gf[k + 1] * Wc1[(size_t)(k + 1) * 512 + t];
            a2 += gf[k + 2] * Wc1[(size_t)(k + 2) * 512 + t];
            a3 += gf[k + 3] * Wc1[(size_t)(k + 3) * 512 + t];
        }
        h1[t] = fmaxf((a0 + a1) + (a2 + a3) + bc1[t], 0.f);
    }
    __syncthreads();
    if (t < 256) {
        float a0 = 0.f, a1 = 0.f, a2 = 0.f, a3 = 0.f;
        for (int k = 0; k < 512; k += 4) {
            a0 += h1[k + 0] * Wc2[(size_t)(k + 0) * 256 + t];
            a1 += h1[k + 1] * Wc2[(size_t)(k + 1) * 256 + t];
            a2 += h1[k + 2] * Wc2[(size_t)(k + 2) * 256 + t];
            a3 += h1[k + 3] * Wc2[(size_t)(k + 3) * 256 + t];
        }
        h2[t] = fmaxf((a0 + a1) + (a2 + a3) + bc2[t], 0.f);
    }
    __syncthreads();
    if (t < 5) {
        float a = bc3[t];
        for (int k = 0; k < 256; ++k) a += h2[k] * Wc3[(size_t)k * 5 + t];
        out[(size_t)g * 5 + t] = a;
    }
}

extern "C" void kernel_launch(void* const* d_in, const int* in_sizes, int n_in, void* d_out,
                              int out_size, void* d_ws, size_t ws_size, hipStream_t stream) {
    const float* x = (const float*)d_in[0];
    const int* eidx = (const int*)d_in[1];
    const int* batch = (const int*)d_in[2];
    const float* W1 = (const float*)d_in[3];
    const float* b1 = (const float*)d_in[4];
    const float* W2 = (const float*)d_in[5];
    const float* b2 = (const float*)d_in[6];
    const float* W3 = (const float*)d_in[7];
    const float* b3 = (const float*)d_in[8];
    const float* Wc1 = (const float*)d_in[9];
    const float* bc1 = (const float*)d_in[10];
    const float* Wc2 = (const float*)d_in[11];
    const float* bc2 = (const float*)d_in[12];
    const float* Wc3 = (const float*)d_in[13];
    const float* bc3 = (const float*)d_in[14];
    float* out = (float*)d_out;

    const int N = in_sizes[2];
    const int E = in_sizes[1] / 2;
    const int G = out_size / 5;
    const int* src = eidx;
    const int* dst = eidx + E;

    char* p = (char*)d_ws;
    auto alloc = [&](size_t bytes) {
        void* r = (void*)p;
        p += (bytes + 255) & ~(size_t)255;
        return r;
    };
    float* dis = (float*)alloc((size_t)N * 4);
    int* degc = (int*)alloc((size_t)N * 4);
    int* row_ptr = (int*)alloc((size_t)(N + 1) * 4);
    int* fill = (int*)alloc((size_t)N * 4);
    const int nch = CDIV(N, 1024);
    int* csum = (int*)alloc((size_t)nch * 4);
    int* coff = (int*)alloc((size_t)nch * 4);
    int* esrc = (int*)alloc((size_t)E * 4);
    float* sumbuf = (float*)alloc((size_t)G * 256 * 4);
    int* maxbuf = (int*)alloc((size_t)G * 256 * 4);
    ushort* Ahi = (ushort*)alloc((size_t)N * 256 * 2);
    ushort* Alo = (ushort*)alloc((size_t)N * 256 * 2);
    ushort* Hhi = (ushort*)alloc((size_t)N * 256 * 2);
    ushort* Xhi = (ushort*)alloc((size_t)N * 128 * 2);
    ushort* W1hi = (ushort*)alloc((size_t)128 * 256 * 2);
    ushort* W1lo = (ushort*)alloc((size_t)128 * 256 * 2);
    ushort* W2hi = (ushort*)alloc((size_t)256 * 256 * 2);
    ushort* W2lo = (ushort*)alloc((size_t)256 * 256 * 2);
    ushort* W3hi = (ushort*)alloc((size_t)256 * 256 * 2);
    ushort* W3lo = (ushort*)alloc((size_t)256 * 256 * 2);
    (void)ws_size;

    // fused prep: xsplit + wsplit x3 + zero(degc,sumbuf,maxbuf)
    {
        const int PB = G * 256;
        const int nx = CDIV(N * 128, 256);
        const int nz = CDIV(PB > N ? PB : N, 256);
        const int nprep = nx + 128 + 256 + 256 + nz;
        k_prep<<<nprep, 256, 0, stream>>>(x, N, Xhi, W1, W1hi, W1lo, W2, W2hi, W2lo, W3, W3hi,
                                          W3lo, degc, sumbuf, maxbuf, PB);
    }

    k_deg<<<CDIV(E, 256), 256, 0, stream>>>(dst, E, degc);
    k_scan_partial<<<nch, 256, 0, stream>>>(degc, N, csum);
    k_scan_chunks<<<1, 64, 0, stream>>>(csum, nch, coff, row_ptr, N, E);
    k_scan_final<<<nch, 256, 0, stream>>>(degc, N, coff, row_ptr, fill, dis);
    k_fill<<<CDIV(E, 256), 256, 0, stream>>>(src, dst, E, row_ptr, fill, esrc);

    const int ggrid = CDIV(N, 64) * 2;

    // layer 1
    k_agg<128, true><<<CDIV(N * 64, 256), 256, 0, stream>>>(x, Xhi, dis, row_ptr, esrc, N,
                                                            Ahi, Alo);
    k_gemm_bf16<128, false><<<ggrid, 256, 0, stream>>>(Ahi, Alo, W1hi, W1lo, b1, N, Hhi,
                                                       batch, sumbuf, maxbuf);
    // layer 2
    k_agg<256, false><<<CDIV(N * 64, 256), 256, 0, stream>>>(nullptr, Hhi, dis, row_ptr,
                                                             esrc, N, Ahi, Alo);
    k_gemm_bf16<256, false><<<ggrid, 256, 0, stream>>>(Ahi, Alo, W2hi, W2lo, b2, N, Hhi,
                                                       batch, sumbuf, maxbuf);
    // layer 3 + fused pooling
    k_agg<256, false><<<CDIV(N * 64, 256), 256, 0, stream>>>(nullptr, Hhi, dis, row_ptr,
                                                             esrc, N, Ahi, Alo);
    k_gemm_bf16<256, true><<<ggrid, 256, 0, stream>>>(Ahi, Alo, W3hi, W3lo, b3, N, Hhi,
                                                      batch, sumbuf, maxbuf);

    // fused pool finalize + MLP head
    k_head<<<G, 512, 0, stream>>>(sumbuf, maxbuf, batch, N, Wc1, bc1, Wc2, bc2, Wc3, bc3, out);
}

// Round 20
// 388.831 us; speedup vs baseline: 1.3845x; 1.0470x over previous
//
#include <hip/hip_runtime.h>
#include <cstdint>

#define CDIV(a, b) (((a) + (b) - 1) / (b))

typedef short bf16x8 __attribute__((ext_vector_type(8)));
typedef float f32x4 __attribute__((ext_vector_type(4)));

__device__ inline ushort f2bf_rn(float f) {
    uint32_t u = __float_as_uint(f);
    uint32_t rounding = 0x7FFF + ((u >> 16) & 1);
    return (ushort)((u + rounding) >> 16);
}
__device__ inline float bf2f(ushort h) { return __uint_as_float((uint32_t)h << 16); }

__device__ inline void wsplit_one(const float* __restrict__ W, int K, ushort* __restrict__ Whi,
                                  ushort* __restrict__ Wlo, int idx) {
    if (idx >= K * 256) return;
    int k = idx >> 8, n = idx & 255;
    float v = W[idx];
    ushort hi = f2bf_rn(v);
    ushort lo = f2bf_rn(v - bf2f(hi));
    int ks = k >> 5, r = k & 31;
    int lane = (r >> 3) * 16 + (n & 15);
    int j = r & 7;
    size_t d = (((size_t)ks * 16 + (n >> 4)) * 64 + lane) * 8 + j;
    Whi[d] = hi;
    Wlo[d] = lo;
}

// ---------------- fused prep: xsplit + 3x wsplit + zero(degc,sumbuf,maxbuf) ----------------
__global__ void k_prep(const float* __restrict__ x, int N, ushort* __restrict__ xhi,
                       const float* __restrict__ W1, ushort* __restrict__ W1hi,
                       ushort* __restrict__ W1lo, const float* __restrict__ W2,
                       ushort* __restrict__ W2hi, ushort* __restrict__ W2lo,
                       const float* __restrict__ W3, ushort* __restrict__ W3hi,
                       ushort* __restrict__ W3lo, int* __restrict__ degc,
                       float* __restrict__ sumbuf, int* __restrict__ maxbuf, int PB) {
    const int nx = CDIV(N * 128, 256);
    const int nz = CDIV(PB > N ? PB : N, 256);
    int b = blockIdx.x;
    int t = threadIdx.x;
    if (b < nx) {
        int i = b * 256 + t;
        if (i < N * 128) xhi[i] = f2bf_rn(x[i]);
        return;
    }
    b -= nx;
    if (b < 128) { wsplit_one(W1, 128, W1hi, W1lo, b * 256 + t); return; }
    b -= 128;
    if (b < 256) { wsplit_one(W2, 256, W2hi, W2lo, b * 256 + t); return; }
    b -= 256;
    if (b < 256) { wsplit_one(W3, 256, W3hi, W3lo, b * 256 + t); return; }
    b -= 256;
    if (b < nz) {
        int i = b * 256 + t;
        if (i < N) degc[i] = 0;
        if (i < PB) { sumbuf[i] = 0.f; maxbuf[i] = 0; }
    }
}

// ---------------- degree ----------------
__global__ void k_deg(const int* __restrict__ dst, int E, int* __restrict__ degc) {
    int e = blockIdx.x * blockDim.x + threadIdx.x;
    if (e < E) atomicAdd(&degc[dst[e]], 1);
}

// ---------------- scan -> row_ptr (+dis, +fill=0) ----------------
__global__ void k_scan_partial(const int* __restrict__ degc, int N, int* __restrict__ csum) {
    __shared__ int sm[256];
    int t = threadIdx.x;
    int idx = blockIdx.x * 1024 + t * 4;
    int s = 0;
#pragma unroll
    for (int j = 0; j < 4; ++j)
        if (idx + j < N) s += degc[idx + j];
    sm[t] = s;
    __syncthreads();
    for (int off = 128; off > 0; off >>= 1) {
        if (t < off) sm[t] += sm[t + off];
        __syncthreads();
    }
    if (t == 0) csum[blockIdx.x] = sm[0];
}

__global__ void k_scan_chunks(const int* __restrict__ csum, int nch, int* __restrict__ coff,
                              int* __restrict__ row_ptr, int N, int E) {
    if (threadIdx.x == 0 && blockIdx.x == 0) {
        int run = 0;
        for (int i = 0; i < nch; ++i) { coff[i] = run; run += csum[i]; }
        row_ptr[N] = E;
    }
}

__global__ void k_scan_final(const int* __restrict__ degc, int N, const int* __restrict__ coff,
                             int* __restrict__ row_ptr, int* __restrict__ fill,
                             float* __restrict__ dis) {
    __shared__ int sm[256];
    int t = threadIdx.x;
    int idx = blockIdx.x * 1024 + t * 4;
    int v[4];
    int s = 0;
#pragma unroll
    for (int j = 0; j < 4; ++j) {
        v[j] = (idx + j < N) ? degc[idx + j] : 0;
        s += v[j];
    }
    sm[t] = s;
    __syncthreads();
    for (int off = 1; off < 256; off <<= 1) {
        int x = (t >= off) ? sm[t - off] : 0;
        __syncthreads();
        sm[t] += x;
        __syncthreads();
    }
    int excl = sm[t] - s + coff[blockIdx.x];
#pragma unroll
    for (int j = 0; j < 4; ++j) {
        if (idx + j < N) {
            row_ptr[idx + j] = excl;
            fill[idx + j] = 0;
            dis[idx + j] = rsqrtf((float)v[j] + 1.0f);
            excl += v[j];
        }
    }
}

// ---------------- CSR fill ----------------
__global__ void k_fill(const int* __restrict__ src, const int* __restrict__ dst, int E,
                       const int* __restrict__ row_ptr, int* __restrict__ fill,
                       int* __restrict__ esrc) {
    int e = blockIdx.x * blockDim.x + threadIdx.x;
    if (e >= E) return;
    int d = dst[e], s = src[e];
    int pos = row_ptr[d] + atomicAdd(&fill[d], 1);
    esrc[pos] = s;
}

// ---------------- aggregation: row-major, one wave per node, bf16-hi output only ----------------
// out[i] = dis_i^2 * self[i] + sum_e dis[s]*dis[i] * hhi[s], rounded to bf16.
// (A-lo plane dropped: error budget allows one more 2^-9 rounding; halves agg
// write traffic and halves the GEMM's A-load latency exposure.)
template <int C, bool SELF_F32>
__global__ __launch_bounds__(256) void k_agg(const float* __restrict__ xf,
                                             const ushort* __restrict__ hhi,
                                             const float* __restrict__ dis,
                                             const int* __restrict__ row_ptr,
                                             const int* __restrict__ esrc, int N,
                                             ushort* __restrict__ ohi) {
    constexpr int V = C / 64;
    int wave = (blockIdx.x * blockDim.x + threadIdx.x) >> 6;
    int lane = threadIdx.x & 63;
    if (wave >= N) return;
    const int i = wave;
    const float di = dis[i];
    const float dd = di * di;
    float acc[V];
    if constexpr (SELF_F32) {
        const float* xr = xf + (size_t)i * C + lane * V;
        if constexpr (V == 4) {
            float4 v = *reinterpret_cast<const float4*>(xr);
            acc[0] = dd * v.x; acc[1] = dd * v.y; acc[2] = dd * v.z; acc[3] = dd * v.w;
        } else {
            float2 v = *reinterpret_cast<const float2*>(xr);
            acc[0] = dd * v.x; acc[1] = dd * v.y;
        }
    } else {
        size_t sb = (size_t)i * C + lane * V;
        if constexpr (V == 4) {
            ushort4 h = *reinterpret_cast<const ushort4*>(hhi + sb);
            acc[0] = dd * bf2f(h.x); acc[1] = dd * bf2f(h.y);
            acc[2] = dd * bf2f(h.z); acc[3] = dd * bf2f(h.w);
        } else {
            ushort2 h = *reinterpret_cast<const ushort2*>(hhi + sb);
            acc[0] = dd * bf2f(h.x); acc[1] = dd * bf2f(h.y);
        }
    }
    const int p0 = row_ptr[i], p1 = row_ptr[i + 1];
    int p = p0;
    if constexpr (V == 4) {
        for (; p + 4 <= p1; p += 4) {
            int s0 = esrc[p], s1 = esrc[p + 1], s2 = esrc[p + 2], s3 = esrc[p + 3];
            float c0 = dis[s0] * di, c1 = dis[s1] * di, c2 = dis[s2] * di, c3 = dis[s3] * di;
            ushort4 v0 = *reinterpret_cast<const ushort4*>(hhi + (size_t)s0 * C + lane * V);
            ushort4 v1 = *reinterpret_cast<const ushort4*>(hhi + (size_t)s1 * C + lane * V);
            ushort4 v2 = *reinterpret_cast<const ushort4*>(hhi + (size_t)s2 * C + lane * V);
            ushort4 v3 = *reinterpret_cast<const ushort4*>(hhi + (size_t)s3 * C + lane * V);
            acc[0] += c0 * bf2f(v0.x); acc[1] += c0 * bf2f(v0.y);
            acc[2] += c0 * bf2f(v0.z); acc[3] += c0 * bf2f(v0.w);
            acc[0] += c1 * bf2f(v1.x); acc[1] += c1 * bf2f(v1.y);
            acc[2] += c1 * bf2f(v1.z); acc[3] += c1 * bf2f(v1.w);
            acc[0] += c2 * bf2f(v2.x); acc[1] += c2 * bf2f(v2.y);
            acc[2] += c2 * bf2f(v2.z); acc[3] += c2 * bf2f(v2.w);
            acc[0] += c3 * bf2f(v3.x); acc[1] += c3 * bf2f(v3.y);
            acc[2] += c3 * bf2f(v3.z); acc[3] += c3 * bf2f(v3.w);
        }
        for (; p < p1; ++p) {
            int s = esrc[p];
            float c = dis[s] * di;
            ushort4 v = *reinterpret_cast<const ushort4*>(hhi + (size_t)s * C + lane * V);
            acc[0] += c * bf2f(v.x); acc[1] += c * bf2f(v.y);
            acc[2] += c * bf2f(v.z); acc[3] += c * bf2f(v.w);
        }
    } else {
        for (; p + 4 <= p1; p += 4) {
            int s0 = esrc[p], s1 = esrc[p + 1], s2 = esrc[p + 2], s3 = esrc[p + 3];
            float c0 = dis[s0] * di, c1 = dis[s1] * di, c2 = dis[s2] * di, c3 = dis[s3] * di;
            ushort2 v0 = *reinterpret_cast<const ushort2*>(hhi + (size_t)s0 * C + lane * V);
            ushort2 v1 = *reinterpret_cast<const ushort2*>(hhi + (size_t)s1 * C + lane * V);
            ushort2 v2 = *reinterpret_cast<const ushort2*>(hhi + (size_t)s2 * C + lane * V);
            ushort2 v3 = *reinterpret_cast<const ushort2*>(hhi + (size_t)s3 * C + lane * V);
            acc[0] += c0 * bf2f(v0.x); acc[1] += c0 * bf2f(v0.y);
            acc[0] += c1 * bf2f(v1.x); acc[1] += c1 * bf2f(v1.y);
            acc[0] += c2 * bf2f(v2.x); acc[1] += c2 * bf2f(v2.y);
            acc[0] += c3 * bf2f(v3.x); acc[1] += c3 * bf2f(v3.y);
        }
        for (; p < p1; ++p) {
            int s = esrc[p];
            float c = dis[s] * di;
            ushort2 v = *reinterpret_cast<const ushort2*>(hhi + (size_t)s * C + lane * V);
            acc[0] += c * bf2f(v.x); acc[1] += c * bf2f(v.y);
        }
    }
    size_t ob = (size_t)i * C + lane * V;
    if constexpr (V == 4) {
        *reinterpret_cast<ushort4*>(ohi + ob) =
            make_ushort4(f2bf_rn(acc[0]), f2bf_rn(acc[1]), f2bf_rn(acc[2]), f2bf_rn(acc[3]));
    } else {
        *reinterpret_cast<ushort2*>(ohi + ob) = make_ushort2(f2bf_rn(acc[0]), f2bf_rn(acc[1]));
    }
}

// ---------------- pipelined bf16 MFMA GEMM, BM=64 BN=128, A = bf16-hi only ----------------
// acc += Ahi*Whi + Ahi*Wlo (W keeps hi/lo split; A single plane -> 1 A-load
// per k-step per wave, halving the latency exposure that set the old floor).
template <int K, bool POOL>
__global__ __launch_bounds__(256) void k_gemm_bf16(const ushort* __restrict__ Ahi,
                                                   const ushort* __restrict__ Whi,
                                                   const ushort* __restrict__ Wlo,
                                                   const float* __restrict__ bias, int M,
                                                   ushort* __restrict__ Hhi,
                                                   const int* __restrict__ batch,
                                                   float* __restrict__ sumbuf,
                                                   int* __restrict__ maxbuf) {
    __shared__ ushort Bs[2][2][8][512];  // 32 KB
    const int t = threadIdx.x;
    const int w = t >> 6, lane = t & 63;
    constexpr int KS = K / 32;

    // bijective XCD-chunked swizzle (m204)
    const int nwg = (int)gridDim.x;
    const int orig = (int)blockIdx.x;
    const int q = nwg >> 3, r = nwg & 7;
    const int xcd = orig & 7;
    const int swz = (xcd < r ? xcd * (q + 1) : r * (q + 1) + (xcd - r) * q) + (orig >> 3);
    const int bm = (swz >> 1) * 64;
    const int bn = (swz & 1) * 128;
    const int rw = bm + w * 16;

    f32x4 acc[8] = {};

    int row0 = min(rw + (lane & 15), M - 1);
    const int kbase = (lane >> 4) * 8;
    const ushort* pa0h = Ahi + (size_t)row0 * K + kbase;
    const int nf0 = bn >> 4;

    bf16x8 sbh[2], sbl[2];
    auto loadB = [&](int ks) {
#pragma unroll
        for (int q2 = 0; q2 < 2; ++q2) {
            int nf = (w << 1) | q2;
            size_t widx = (((size_t)ks * 16 + nf0 + nf) * 64 + lane) * 8;
            sbh[q2] = *reinterpret_cast<const bf16x8*>(Whi + widx);
            sbl[q2] = *reinterpret_cast<const bf16x8*>(Wlo + widx);
        }
    };
    auto writeB = [&](int b) {
#pragma unroll
        for (int q2 = 0; q2 < 2; ++q2) {
            int nf = (w << 1) | q2;
            *reinterpret_cast<bf16x8*>(&Bs[b][0][nf][lane * 8]) = sbh[q2];
            *reinterpret_cast<bf16x8*>(&Bs[b][1][nf][lane * 8]) = sbl[q2];
        }
    };

    bf16x8 c0h, n0h, m0h;
    auto loadA = [&](int ks, bf16x8& xh) {
        xh = *reinterpret_cast<const bf16x8*>(pa0h + ks * 32);
    };

    loadB(0);
    writeB(0);
    loadA(0, c0h);
    if (KS > 1) loadA(1, n0h);
    if (KS > 1) loadB(1);
    __syncthreads();

#pragma unroll
    for (int ks = 0; ks < KS; ++ks) {
        const int buf = ks & 1;
        if (ks + 2 < KS) loadA(ks + 2, m0h);
#pragma unroll
        for (int nf = 0; nf < 8; ++nf) {
            bf16x8 bh = *reinterpret_cast<const bf16x8*>(&Bs[buf][0][nf][lane * 8]);
            bf16x8 bl = *reinterpret_cast<const bf16x8*>(&Bs[buf][1][nf][lane * 8]);
            acc[nf] = __builtin_amdgcn_mfma_f32_16x16x32_bf16(c0h, bh, acc[nf], 0, 0, 0);
            acc[nf] = __builtin_amdgcn_mfma_f32_16x16x32_bf16(c0h, bl, acc[nf], 0, 0, 0);
        }
        if (ks + 1 < KS) {
            writeB(buf ^ 1);
            if (ks + 2 < KS) loadB(ks + 2);
            __syncthreads();
            c0h = n0h;
            n0h = m0h;
        }
    }

    const int colq = lane & 15;
    const int rowq = (lane >> 4) * 4;

    if constexpr (!POOL) {
#pragma unroll
        for (int nf = 0; nf < 8; ++nf) {
            int col = bn + nf * 16 + colq;
            float bia = bias[col];
#pragma unroll
            for (int r2 = 0; r2 < 4; ++r2) {
                int rr = rw + rowq + r2;
                if (rr < M) {
                    float v = fmaxf(acc[nf][r2] + bia, 0.f);
                    Hhi[(size_t)rr * 256 + col] = f2bf_rn(v);
                }
            }
        }
    } else {
        int r0 = min(rw + rowq, M - 1);
        int r3 = min(rw + rowq + 3, M - 1);
        int g0 = batch[r0];
        int g3 = batch[r3];
        int gfirst = __shfl(g0, 0);
        bool uni = __all(g0 == gfirst && g3 == gfirst);
        if (uni) {
#pragma unroll
            for (int nf = 0; nf < 8; ++nf) {
                int col = bn + nf * 16 + colq;
                float bia = bias[col];
                float s = 0.f, mx = 0.f;
#pragma unroll
                for (int r2 = 0; r2 < 4; ++r2) {
                    int rr = rw + rowq + r2;
                    float v = fmaxf(acc[nf][r2] + bia, 0.f);
                    if (rr < M) { s += v; mx = fmaxf(mx, v); }
                }
                s += __shfl_xor(s, 16);
                mx = fmaxf(mx, __shfl_xor(mx, 16));
                s += __shfl_xor(s, 32);
                mx = fmaxf(mx, __shfl_xor(mx, 32));
                if ((lane >> 4) == 0) {
                    atomicAdd(&sumbuf[gfirst * 256 + col], s);
                    atomicMax(&maxbuf[gfirst * 256 + col], __float_as_int(mx));
                }
            }
        } else {
#pragma unroll
            for (int nf = 0; nf < 8; ++nf) {
                int col = bn + nf * 16 + colq;
                float bia = bias[col];
#pragma unroll
                for (int r2 = 0; r2 < 4; ++r2) {
                    int rr = rw + rowq + r2;
                    if (rr < M) {
                        float v = fmaxf(acc[nf][r2] + bia, 0.f);
                        int g = batch[rr];
                        atomicAdd(&sumbuf[g * 256 + col], v);
                        atomicMax(&maxbuf[g * 256 + col], __float_as_int(v));
                    }
                }
            }
        }
    }
}

// ---------------- fused pool-finalize + 3-layer MLP head ----------------
__global__ __launch_bounds__(512) void k_head(const float* __restrict__ sumbuf,
                                              const int* __restrict__ maxbuf,
                                              const int* __restrict__ batch, int N,
                                              const float* __restrict__ Wc1,
                                              const float* __restrict__ bc1,
                                              const float* __restrict__ Wc2,
                                              const float* __restrict__ bc2,
                                              const float* __restrict__ Wc3,
                                              const float* __restrict__ bc3,
                                              float* __restrict__ out) {
    __shared__ float gf[512];
    __shared__ float h1[512];
    __shared__ float h2[256];
    __shared__ int cntS;
    const int g = blockIdx.x;
    const int t = threadIdx.x;

    if (t == 0) {
        int lo = 0, hi = N;
        while (lo < hi) { int mid = (lo + hi) >> 1; if (batch[mid] < g) lo = mid + 1; else hi = mid; }
        int s = lo;
        lo = 0; hi = N;
        while (lo < hi) { int mid = (lo + hi) >> 1; if (batch[mid] < g + 1) lo = mid + 1; else hi = mid; }
        cntS = lo - s;
    }
    __syncthreads();
    const int cnt = cntS;
    if (t < 256) {
        float mean = sumbuf[g * 256 + t] / fmaxf((float)cnt, 1.0f);
        float mx = __int_as_float(maxbuf[g * 256 + t]);
        if (cnt == 0) { mean = 0.f; mx = 0.f; }
        gf[t] = mean;
        gf[256 + t] = mx;
    }
    __syncthreads();
    {
        float a0 = 0.f, a1 = 0.f, a2 = 0.f, a3 = 0.f;
        for (int k = 0; k < 512; k += 4) {
            a0 += gf[k + 0] * Wc1[(size_t)(k + 0) * 512 + t];
            a1 += gf[k + 1] * Wc1[(size_t)(k + 1) * 512 + t];
            a2 += gf[k + 2] * Wc1[(size_t)(k + 2) * 512 + t];
            a3 += gf[k + 3] * Wc1[(size_t)(k + 3) * 512 + t];
        }
        h1[t] = fmaxf((a0 + a1) + (a2 + a3) + bc1[t], 0.f);
    }
    __syncthreads();
    if (t < 256) {
        float a0 = 0.f, a1 = 0.f, a2 = 0.f, a3 = 0.f;
        for (int k = 0; k < 512; k += 4) {
            a0 += h1[k + 0] * Wc2[(size_t)(k + 0) * 256 + t];
            a1 += h1[k + 1] * Wc2[(size_t)(k + 1) * 256 + t];
            a2 += h1[k + 2] * Wc2[(size_t)(k + 2) * 256 + t];
            a3 += h1[k + 3] * Wc2[(size_t)(k + 3) * 256 + t];
        }
        h2[t] = fmaxf((a0 + a1) + (a2 + a3) + bc2[t], 0.f);
    }
    __syncthreads();
    if (t < 5) {
        float a = bc3[t];
        for (int k = 0; k < 256; ++k) a += h2[k] * Wc3[(size_t)k * 5 + t];
        out[(size_t)g * 5 + t] = a;
    }
}

extern "C" void kernel_launch(void* const* d_in, const int* in_sizes, int n_in, void* d_out,
                              int out_size, void* d_ws, size_t ws_size, hipStream_t stream) {
    const float* x = (const float*)d_in[0];
    const int* eidx = (const int*)d_in[1];
    const int* batch = (const int*)d_in[2];
    const float* W1 = (const float*)d_in[3];
    const float* b1 = (const float*)d_in[4];
    const float* W2 = (const float*)d_in[5];
    const float* b2 = (const float*)d_in[6];
    const float* W3 = (const float*)d_in[7];
    const float* b3 = (const float*)d_in[8];
    const float* Wc1 = (const float*)d_in[9];
    const float* bc1 = (const float*)d_in[10];
    const float* Wc2 = (const float*)d_in[11];
    const float* bc2 = (const float*)d_in[12];
    const float* Wc3 = (const float*)d_in[13];
    const float* bc3 = (const float*)d_in[14];
    float* out = (float*)d_out;

    const int N = in_sizes[2];
    const int E = in_sizes[1] / 2;
    const int G = out_size / 5;
    const int* src = eidx;
    const int* dst = eidx + E;

    char* p = (char*)d_ws;
    auto alloc = [&](size_t bytes) {
        void* r = (void*)p;
        p += (bytes + 255) & ~(size_t)255;
        return r;
    };
    float* dis = (float*)alloc((size_t)N * 4);
    int* degc = (int*)alloc((size_t)N * 4);
    int* row_ptr = (int*)alloc((size_t)(N + 1) * 4);
    int* fill = (int*)alloc((size_t)N * 4);
    const int nch = CDIV(N, 1024);
    int* csum = (int*)alloc((size_t)nch * 4);
    int* coff = (int*)alloc((size_t)nch * 4);
    int* esrc = (int*)alloc((size_t)E * 4);
    float* sumbuf = (float*)alloc((size_t)G * 256 * 4);
    int* maxbuf = (int*)alloc((size_t)G * 256 * 4);
    ushort* Ahi = (ushort*)alloc((size_t)N * 256 * 2);
    ushort* Hhi = (ushort*)alloc((size_t)N * 256 * 2);
    ushort* Xhi = (ushort*)alloc((size_t)N * 128 * 2);
    ushort* W1hi = (ushort*)alloc((size_t)128 * 256 * 2);
    ushort* W1lo = (ushort*)alloc((size_t)128 * 256 * 2);
    ushort* W2hi = (ushort*)alloc((size_t)256 * 256 * 2);
    ushort* W2lo = (ushort*)alloc((size_t)256 * 256 * 2);
    ushort* W3hi = (ushort*)alloc((size_t)256 * 256 * 2);
    ushort* W3lo = (ushort*)alloc((size_t)256 * 256 * 2);
    (void)ws_size;

    // fused prep: xsplit + wsplit x3 + zero(degc,sumbuf,maxbuf)
    {
        const int PB = G * 256;
        const int nx = CDIV(N * 128, 256);
        const int nz = CDIV(PB > N ? PB : N, 256);
        const int nprep = nx + 128 + 256 + 256 + nz;
        k_prep<<<nprep, 256, 0, stream>>>(x, N, Xhi, W1, W1hi, W1lo, W2, W2hi, W2lo, W3, W3hi,
                                          W3lo, degc, sumbuf, maxbuf, PB);
    }

    k_deg<<<CDIV(E, 256), 256, 0, stream>>>(dst, E, degc);
    k_scan_partial<<<nch, 256, 0, stream>>>(degc, N, csum);
    k_scan_chunks<<<1, 64, 0, stream>>>(csum, nch, coff, row_ptr, N, E);
    k_scan_final<<<nch, 256, 0, stream>>>(degc, N, coff, row_ptr, fill, dis);
    k_fill<<<CDIV(E, 256), 256, 0, stream>>>(src, dst, E, row_ptr, fill, esrc);

    const int ggrid = CDIV(N, 64) * 2;

    // layer 1
    k_agg<128, true><<<CDIV(N * 64, 256), 256, 0, stream>>>(x, Xhi, dis, row_ptr, esrc, N, Ahi);
    k_gemm_bf16<128, false><<<ggrid, 256, 0, stream>>>(Ahi, W1hi, W1lo, b1, N, Hhi,
                                                       batch, sumbuf, maxbuf);
    // layer 2
    k_agg<256, false><<<CDIV(N * 64, 256), 256, 0, stream>>>(nullptr, Hhi, dis, row_ptr,
                                                             esrc, N, Ahi);
    k_gemm_bf16<256, false><<<ggrid, 256, 0, stream>>>(Ahi, W2hi, W2lo, b2, N, Hhi,
                                                       batch, sumbuf, maxbuf);
    // layer 3 + fused pooling
    k_agg<256, false><<<CDIV(N * 64, 256), 256, 0, stream>>>(nullptr, Hhi, dis, row_ptr,
                                                             esrc, N, Ahi);
    k_gemm_bf16<256, true><<<ggrid, 256, 0, stream>>>(Ahi, W3hi, W3lo, b3, N, Hhi,
                                                      batch, sumbuf, maxbuf);

    // fused pool finalize + MLP head
    k_head<<<G, 512, 0, stream>>>(sumbuf, maxbuf, batch, N, Wc1, bc1, Wc2, bc2, Wc3, bc3, out);
}

// Round 21
// 376.701 us; speedup vs baseline: 1.4291x; 1.0322x over previous
//
#include <hip/hip_runtime.h>
#include <cstdint>

#define CDIV(a, b) (((a) + (b) - 1) / (b))

typedef short bf16x8 __attribute__((ext_vector_type(8)));
typedef float f32x4 __attribute__((ext_vector_type(4)));

__device__ inline ushort f2bf_rn(float f) {
    uint32_t u = __float_as_uint(f);
    uint32_t rounding = 0x7FFF + ((u >> 16) & 1);
    return (ushort)((u + rounding) >> 16);
}
__device__ inline float bf2f(ushort h) { return __uint_as_float((uint32_t)h << 16); }

__device__ inline void wsplit_one(const float* __restrict__ W, int K, ushort* __restrict__ Whi,
                                  int idx) {
    if (idx >= K * 256) return;
    int k = idx >> 8, n = idx & 255;
    ushort hi = f2bf_rn(W[idx]);
    int ks = k >> 5, r = k & 31;
    int lane = (r >> 3) * 16 + (n & 15);
    int j = r & 7;
    size_t d = (((size_t)ks * 16 + (n >> 4)) * 64 + lane) * 8 + j;
    Whi[d] = hi;
}

// ---------------- fused prep: xsplit + 3x wsplit + zero(degc,sumbuf,maxbuf) ----------------
__global__ void k_prep(const float* __restrict__ x, int N, ushort* __restrict__ xhi,
                       const float* __restrict__ W1, ushort* __restrict__ W1hi,
                       const float* __restrict__ W2, ushort* __restrict__ W2hi,
                       const float* __restrict__ W3, ushort* __restrict__ W3hi,
                       int* __restrict__ degc, float* __restrict__ sumbuf,
                       int* __restrict__ maxbuf, int PB) {
    const int nx = CDIV(N * 128, 256);
    const int nz = CDIV(PB > N ? PB : N, 256);
    int b = blockIdx.x;
    int t = threadIdx.x;
    if (b < nx) {
        int i = b * 256 + t;
        if (i < N * 128) xhi[i] = f2bf_rn(x[i]);
        return;
    }
    b -= nx;
    if (b < 128) { wsplit_one(W1, 128, W1hi, b * 256 + t); return; }
    b -= 128;
    if (b < 256) { wsplit_one(W2, 256, W2hi, b * 256 + t); return; }
    b -= 256;
    if (b < 256) { wsplit_one(W3, 256, W3hi, b * 256 + t); return; }
    b -= 256;
    if (b < nz) {
        int i = b * 256 + t;
        if (i < N) degc[i] = 0;
        if (i < PB) { sumbuf[i] = 0.f; maxbuf[i] = 0; }
    }
}

// ---------------- degree ----------------
__global__ void k_deg(const int* __restrict__ dst, int E, int* __restrict__ degc) {
    int e = blockIdx.x * blockDim.x + threadIdx.x;
    if (e < E) atomicAdd(&degc[dst[e]], 1);
}

// ---------------- scan -> row_ptr (+dis, +fill=0) ----------------
__global__ void k_scan_partial(const int* __restrict__ degc, int N, int* __restrict__ csum) {
    __shared__ int sm[256];
    int t = threadIdx.x;
    int idx = blockIdx.x * 1024 + t * 4;
    int s = 0;
#pragma unroll
    for (int j = 0; j < 4; ++j)
        if (idx + j < N) s += degc[idx + j];
    sm[t] = s;
    __syncthreads();
    for (int off = 128; off > 0; off >>= 1) {
        if (t < off) sm[t] += sm[t + off];
        __syncthreads();
    }
    if (t == 0) csum[blockIdx.x] = sm[0];
}

__global__ void k_scan_chunks(const int* __restrict__ csum, int nch, int* __restrict__ coff,
                              int* __restrict__ row_ptr, int N, int E) {
    if (threadIdx.x == 0 && blockIdx.x == 0) {
        int run = 0;
        for (int i = 0; i < nch; ++i) { coff[i] = run; run += csum[i]; }
        row_ptr[N] = E;
    }
}

__global__ void k_scan_final(const int* __restrict__ degc, int N, const int* __restrict__ coff,
                             int* __restrict__ row_ptr, int* __restrict__ fill,
                             float* __restrict__ dis) {
    __shared__ int sm[256];
    int t = threadIdx.x;
    int idx = blockIdx.x * 1024 + t * 4;
    int v[4];
    int s = 0;
#pragma unroll
    for (int j = 0; j < 4; ++j) {
        v[j] = (idx + j < N) ? degc[idx + j] : 0;
        s += v[j];
    }
    sm[t] = s;
    __syncthreads();
    for (int off = 1; off < 256; off <<= 1) {
        int x = (t >= off) ? sm[t - off] : 0;
        __syncthreads();
        sm[t] += x;
        __syncthreads();
    }
    int excl = sm[t] - s + coff[blockIdx.x];
#pragma unroll
    for (int j = 0; j < 4; ++j) {
        if (idx + j < N) {
            row_ptr[idx + j] = excl;
            fill[idx + j] = 0;
            dis[idx + j] = rsqrtf((float)v[j] + 1.0f);
            excl += v[j];
        }
    }
}

// ---------------- CSR fill ----------------
__global__ void k_fill(const int* __restrict__ src, const int* __restrict__ dst, int E,
                       const int* __restrict__ row_ptr, int* __restrict__ fill,
                       int* __restrict__ esrc) {
    int e = blockIdx.x * blockDim.x + threadIdx.x;
    if (e >= E) return;
    int d = dst[e], s = src[e];
    int pos = row_ptr[d] + atomicAdd(&fill[d], 1);
    esrc[pos] = s;
}

// ---------------- aggregation: row-major, one wave per node, bf16-hi output ----------------
template <int C, bool SELF_F32>
__global__ __launch_bounds__(256) void k_agg(const float* __restrict__ xf,
                                             const ushort* __restrict__ hhi,
                                             const float* __restrict__ dis,
                                             const int* __restrict__ row_ptr,
                                             const int* __restrict__ esrc, int N,
                                             ushort* __restrict__ ohi) {
    constexpr int V = C / 64;
    int wave = (blockIdx.x * blockDim.x + threadIdx.x) >> 6;
    int lane = threadIdx.x & 63;
    if (wave >= N) return;
    const int i = wave;
    const float di = dis[i];
    const float dd = di * di;
    float acc[V];
    if constexpr (SELF_F32) {
        const float* xr = xf + (size_t)i * C + lane * V;
        if constexpr (V == 4) {
            float4 v = *reinterpret_cast<const float4*>(xr);
            acc[0] = dd * v.x; acc[1] = dd * v.y; acc[2] = dd * v.z; acc[3] = dd * v.w;
        } else {
            float2 v = *reinterpret_cast<const float2*>(xr);
            acc[0] = dd * v.x; acc[1] = dd * v.y;
        }
    } else {
        size_t sb = (size_t)i * C + lane * V;
        if constexpr (V == 4) {
            ushort4 h = *reinterpret_cast<const ushort4*>(hhi + sb);
            acc[0] = dd * bf2f(h.x); acc[1] = dd * bf2f(h.y);
            acc[2] = dd * bf2f(h.z); acc[3] = dd * bf2f(h.w);
        } else {
            ushort2 h = *reinterpret_cast<const ushort2*>(hhi + sb);
            acc[0] = dd * bf2f(h.x); acc[1] = dd * bf2f(h.y);
        }
    }
    const int p0 = row_ptr[i], p1 = row_ptr[i + 1];
    int p = p0;
    if constexpr (V == 4) {
        for (; p + 4 <= p1; p += 4) {
            int s0 = esrc[p], s1 = esrc[p + 1], s2 = esrc[p + 2], s3 = esrc[p + 3];
            float c0 = dis[s0] * di, c1 = dis[s1] * di, c2 = dis[s2] * di, c3 = dis[s3] * di;
            ushort4 v0 = *reinterpret_cast<const ushort4*>(hhi + (size_t)s0 * C + lane * V);
            ushort4 v1 = *reinterpret_cast<const ushort4*>(hhi + (size_t)s1 * C + lane * V);
            ushort4 v2 = *reinterpret_cast<const ushort4*>(hhi + (size_t)s2 * C + lane * V);
            ushort4 v3 = *reinterpret_cast<const ushort4*>(hhi + (size_t)s3 * C + lane * V);
            acc[0] += c0 * bf2f(v0.x); acc[1] += c0 * bf2f(v0.y);
            acc[2] += c0 * bf2f(v0.z); acc[3] += c0 * bf2f(v0.w);
            acc[0] += c1 * bf2f(v1.x); acc[1] += c1 * bf2f(v1.y);
            acc[2] += c1 * bf2f(v1.z); acc[3] += c1 * bf2f(v1.w);
            acc[0] += c2 * bf2f(v2.x); acc[1] += c2 * bf2f(v2.y);
            acc[2] += c2 * bf2f(v2.z); acc[3] += c2 * bf2f(v2.w);
            acc[0] += c3 * bf2f(v3.x); acc[1] += c3 * bf2f(v3.y);
            acc[2] += c3 * bf2f(v3.z); acc[3] += c3 * bf2f(v3.w);
        }
        for (; p < p1; ++p) {
            int s = esrc[p];
            float c = dis[s] * di;
            ushort4 v = *reinterpret_cast<const ushort4*>(hhi + (size_t)s * C + lane * V);
            acc[0] += c * bf2f(v.x); acc[1] += c * bf2f(v.y);
            acc[2] += c * bf2f(v.z); acc[3] += c * bf2f(v.w);
        }
    } else {
        for (; p + 4 <= p1; p += 4) {
            int s0 = esrc[p], s1 = esrc[p + 1], s2 = esrc[p + 2], s3 = esrc[p + 3];
            float c0 = dis[s0] * di, c1 = dis[s1] * di, c2 = dis[s2] * di, c3 = dis[s3] * di;
            ushort2 v0 = *reinterpret_cast<const ushort2*>(hhi + (size_t)s0 * C + lane * V);
            ushort2 v1 = *reinterpret_cast<const ushort2*>(hhi + (size_t)s1 * C + lane * V);
            ushort2 v2 = *reinterpret_cast<const ushort2*>(hhi + (size_t)s2 * C + lane * V);
            ushort2 v3 = *reinterpret_cast<const ushort2*>(hhi + (size_t)s3 * C + lane * V);
            acc[0] += c0 * bf2f(v0.x); acc[1] += c0 * bf2f(v0.y);
            acc[0] += c1 * bf2f(v1.x); acc[1] += c1 * bf2f(v1.y);
            acc[0] += c2 * bf2f(v2.x); acc[1] += c2 * bf2f(v2.y);
            acc[0] += c3 * bf2f(v3.x); acc[1] += c3 * bf2f(v3.y);
        }
        for (; p < p1; ++p) {
            int s = esrc[p];
            float c = dis[s] * di;
            ushort2 v = *reinterpret_cast<const ushort2*>(hhi + (size_t)s * C + lane * V);
            acc[0] += c * bf2f(v.x); acc[1] += c * bf2f(v.y);
        }
    }
    size_t ob = (size_t)i * C + lane * V;
    if constexpr (V == 4) {
        *reinterpret_cast<ushort4*>(ohi + ob) =
            make_ushort4(f2bf_rn(acc[0]), f2bf_rn(acc[1]), f2bf_rn(acc[2]), f2bf_rn(acc[3]));
    } else {
        *reinterpret_cast<ushort2*>(ohi + ob) = make_ushort2(f2bf_rn(acc[0]), f2bf_rn(acc[1]));
    }
}

// ---------------- pipelined bf16 MFMA GEMM, BM=64 BN=128, pure bf16 A and W ----------------
// acc += Ahi*Whi (W-lo dropped too: error budget slack per R20 measurement;
// halves MFMA work and B LDS traffic, LDS 16 KB -> higher occupancy).
template <int K, bool POOL>
__global__ __launch_bounds__(256) void k_gemm_bf16(const ushort* __restrict__ Ahi,
                                                   const ushort* __restrict__ Whi,
                                                   const float* __restrict__ bias, int M,
                                                   ushort* __restrict__ Hhi,
                                                   const int* __restrict__ batch,
                                                   float* __restrict__ sumbuf,
                                                   int* __restrict__ maxbuf) {
    __shared__ ushort Bs[2][8][512];  // 16 KB
    const int t = threadIdx.x;
    const int w = t >> 6, lane = t & 63;
    constexpr int KS = K / 32;

    // bijective XCD-chunked swizzle (m204)
    const int nwg = (int)gridDim.x;
    const int orig = (int)blockIdx.x;
    const int q = nwg >> 3, r = nwg & 7;
    const int xcd = orig & 7;
    const int swz = (xcd < r ? xcd * (q + 1) : r * (q + 1) + (xcd - r) * q) + (orig >> 3);
    const int bm = (swz >> 1) * 64;
    const int bn = (swz & 1) * 128;
    const int rw = bm + w * 16;

    f32x4 acc[8] = {};

    int row0 = min(rw + (lane & 15), M - 1);
    const int kbase = (lane >> 4) * 8;
    const ushort* pa0h = Ahi + (size_t)row0 * K + kbase;
    const int nf0 = bn >> 4;

    bf16x8 sbh[2];
    auto loadB = [&](int ks) {
#pragma unroll
        for (int q2 = 0; q2 < 2; ++q2) {
            int nf = (w << 1) | q2;
            size_t widx = (((size_t)ks * 16 + nf0 + nf) * 64 + lane) * 8;
            sbh[q2] = *reinterpret_cast<const bf16x8*>(Whi + widx);
        }
    };
    auto writeB = [&](int b) {
#pragma unroll
        for (int q2 = 0; q2 < 2; ++q2) {
            int nf = (w << 1) | q2;
            *reinterpret_cast<bf16x8*>(&Bs[b][nf][lane * 8]) = sbh[q2];
        }
    };

    bf16x8 c0h, n0h, m0h;
    auto loadA = [&](int ks, bf16x8& xh) {
        xh = *reinterpret_cast<const bf16x8*>(pa0h + ks * 32);
    };

    loadB(0);
    writeB(0);
    loadA(0, c0h);
    if (KS > 1) loadA(1, n0h);
    if (KS > 1) loadB(1);
    __syncthreads();

#pragma unroll
    for (int ks = 0; ks < KS; ++ks) {
        const int buf = ks & 1;
        if (ks + 2 < KS) loadA(ks + 2, m0h);
#pragma unroll
        for (int nf = 0; nf < 8; ++nf) {
            bf16x8 bh = *reinterpret_cast<const bf16x8*>(&Bs[buf][nf][lane * 8]);
            acc[nf] = __builtin_amdgcn_mfma_f32_16x16x32_bf16(c0h, bh, acc[nf], 0, 0, 0);
        }
        if (ks + 1 < KS) {
            writeB(buf ^ 1);
            if (ks + 2 < KS) loadB(ks + 2);
            __syncthreads();
            c0h = n0h;
            n0h = m0h;
        }
    }

    const int colq = lane & 15;
    const int rowq = (lane >> 4) * 4;

    if constexpr (!POOL) {
#pragma unroll
        for (int nf = 0; nf < 8; ++nf) {
            int col = bn + nf * 16 + colq;
            float bia = bias[col];
#pragma unroll
            for (int r2 = 0; r2 < 4; ++r2) {
                int rr = rw + rowq + r2;
                if (rr < M) {
                    float v = fmaxf(acc[nf][r2] + bia, 0.f);
                    Hhi[(size_t)rr * 256 + col] = f2bf_rn(v);
                }
            }
        }
    } else {
        int r0 = min(rw + rowq, M - 1);
        int r3 = min(rw + rowq + 3, M - 1);
        int g0 = batch[r0];
        int g3 = batch[r3];
        int gfirst = __shfl(g0, 0);
        bool uni = __all(g0 == gfirst && g3 == gfirst);
        if (uni) {
#pragma unroll
            for (int nf = 0; nf < 8; ++nf) {
                int col = bn + nf * 16 + colq;
                float bia = bias[col];
                float s = 0.f, mx = 0.f;
#pragma unroll
                for (int r2 = 0; r2 < 4; ++r2) {
                    int rr = rw + rowq + r2;
                    float v = fmaxf(acc[nf][r2] + bia, 0.f);
                    if (rr < M) { s += v; mx = fmaxf(mx, v); }
                }
                s += __shfl_xor(s, 16);
                mx = fmaxf(mx, __shfl_xor(mx, 16));
                s += __shfl_xor(s, 32);
                mx = fmaxf(mx, __shfl_xor(mx, 32));
                if ((lane >> 4) == 0) {
                    atomicAdd(&sumbuf[gfirst * 256 + col], s);
                    atomicMax(&maxbuf[gfirst * 256 + col], __float_as_int(mx));
                }
            }
        } else {
#pragma unroll
            for (int nf = 0; nf < 8; ++nf) {
                int col = bn + nf * 16 + colq;
                float bia = bias[col];
#pragma unroll
                for (int r2 = 0; r2 < 4; ++r2) {
                    int rr = rw + rowq + r2;
                    if (rr < M) {
                        float v = fmaxf(acc[nf][r2] + bia, 0.f);
                        int g = batch[rr];
                        atomicAdd(&sumbuf[g * 256 + col], v);
                        atomicMax(&maxbuf[g * 256 + col], __float_as_int(v));
                    }
                }
            }
        }
    }
}

// ---------------- fused pool-finalize + 3-layer MLP head ----------------
__global__ __launch_bounds__(512) void k_head(const float* __restrict__ sumbuf,
                                              const int* __restrict__ maxbuf,
                                              const int* __restrict__ batch, int N,
                                              const float* __restrict__ Wc1,
                                              const float* __restrict__ bc1,
                                              const float* __restrict__ Wc2,
                                              const float* __restrict__ bc2,
                                              const float* __restrict__ Wc3,
                                              const float* __restrict__ bc3,
                                              float* __restrict__ out) {
    __shared__ float gf[512];
    __shared__ float h1[512];
    __shared__ float h2[256];
    __shared__ int cntS;
    const int g = blockIdx.x;
    const int t = threadIdx.x;

    if (t == 0) {
        int lo = 0, hi = N;
        while (lo < hi) { int mid = (lo + hi) >> 1; if (batch[mid] < g) lo = mid + 1; else hi = mid; }
        int s = lo;
        lo = 0; hi = N;
        while (lo < hi) { int mid = (lo + hi) >> 1; if (batch[mid] < g + 1) lo = mid + 1; else hi = mid; }
        cntS = lo - s;
    }
    __syncthreads();
    const int cnt = cntS;
    if (t < 256) {
        float mean = sumbuf[g * 256 + t] / fmaxf((float)cnt, 1.0f);
        float mx = __int_as_float(maxbuf[g * 256 + t]);
        if (cnt == 0) { mean = 0.f; mx = 0.f; }
        gf[t] = mean;
        gf[256 + t] = mx;
    }
    __syncthreads();
    {
        float a0 = 0.f, a1 = 0.f, a2 = 0.f, a3 = 0.f;
        for (int k = 0; k < 512; k += 4) {
            a0 += gf[k + 0] * Wc1[(size_t)(k + 0) * 512 + t];
            a1 += gf[k + 1] * Wc1[(size_t)(k + 1) * 512 + t];
            a2 += gf[k + 2] * Wc1[(size_t)(k + 2) * 512 + t];
            a3 += gf[k + 3] * Wc1[(size_t)(k + 3) * 512 + t];
        }
        h1[t] = fmaxf((a0 + a1) + (a2 + a3) + bc1[t], 0.f);
    }
    __syncthreads();
    if (t < 256) {
        float a0 = 0.f, a1 = 0.f, a2 = 0.f, a3 = 0.f;
        for (int k = 0; k < 512; k += 4) {
            a0 += h1[k + 0] * Wc2[(size_t)(k + 0) * 256 + t];
            a1 += h1[k + 1] * Wc2[(size_t)(k + 1) * 256 + t];
            a2 += h1[k + 2] * Wc2[(size_t)(k + 2) * 256 + t];
            a3 += h1[k + 3] * Wc2[(size_t)(k + 3) * 256 + t];
        }
        h2[t] = fmaxf((a0 + a1) + (a2 + a3) + bc2[t], 0.f);
    }
    __syncthreads();
    if (t < 5) {
        float a = bc3[t];
        for (int k = 0; k < 256; ++k) a += h2[k] * Wc3[(size_t)k * 5 + t];
        out[(size_t)g * 5 + t] = a;
    }
}

extern "C" void kernel_launch(void* const* d_in, const int* in_sizes, int n_in, void* d_out,
                              int out_size, void* d_ws, size_t ws_size, hipStream_t stream) {
    const float* x = (const float*)d_in[0];
    const int* eidx = (const int*)d_in[1];
    const int* batch = (const int*)d_in[2];
    const float* W1 = (const float*)d_in[3];
    const float* b1 = (const float*)d_in[4];
    const float* W2 = (const float*)d_in[5];
    const float* b2 = (const float*)d_in[6];
    const float* W3 = (const float*)d_in[7];
    const float* b3 = (const float*)d_in[8];
    const float* Wc1 = (const float*)d_in[9];
    const float* bc1 = (const float*)d_in[10];
    const float* Wc2 = (const float*)d_in[11];
    const float* bc2 = (const float*)d_in[12];
    const float* Wc3 = (const float*)d_in[13];
    const float* bc3 = (const float*)d_in[14];
    float* out = (float*)d_out;

    const int N = in_sizes[2];
    const int E = in_sizes[1] / 2;
    const int G = out_size / 5;
    const int* src = eidx;
    const int* dst = eidx + E;

    char* p = (char*)d_ws;
    auto alloc = [&](size_t bytes) {
        void* r = (void*)p;
        p += (bytes + 255) & ~(size_t)255;
        return r;
    };
    float* dis = (float*)alloc((size_t)N * 4);
    int* degc = (int*)alloc((size_t)N * 4);
    int* row_ptr = (int*)alloc((size_t)(N + 1) * 4);
    int* fill = (int*)alloc((size_t)N * 4);
    const int nch = CDIV(N, 1024);
    int* csum = (int*)alloc((size_t)nch * 4);
    int* coff = (int*)alloc((size_t)nch * 4);
    int* esrc = (int*)alloc((size_t)E * 4);
    float* sumbuf = (float*)alloc((size_t)G * 256 * 4);
    int* maxbuf = (int*)alloc((size_t)G * 256 * 4);
    ushort* Ahi = (ushort*)alloc((size_t)N * 256 * 2);
    ushort* Hhi = (ushort*)alloc((size_t)N * 256 * 2);
    ushort* Xhi = (ushort*)alloc((size_t)N * 128 * 2);
    ushort* W1hi = (ushort*)alloc((size_t)128 * 256 * 2);
    ushort* W2hi = (ushort*)alloc((size_t)256 * 256 * 2);
    ushort* W3hi = (ushort*)alloc((size_t)256 * 256 * 2);
    (void)ws_size;

    // fused prep: xsplit + wsplit x3 + zero(degc,sumbuf,maxbuf)
    {
        const int PB = G * 256;
        const int nx = CDIV(N * 128, 256);
        const int nz = CDIV(PB > N ? PB : N, 256);
        const int nprep = nx + 128 + 256 + 256 + nz;
        k_prep<<<nprep, 256, 0, stream>>>(x, N, Xhi, W1, W1hi, W2, W2hi, W3, W3hi,
                                          degc, sumbuf, maxbuf, PB);
    }

    k_deg<<<CDIV(E, 256), 256, 0, stream>>>(dst, E, degc);
    k_scan_partial<<<nch, 256, 0, stream>>>(degc, N, csum);
    k_scan_chunks<<<1, 64, 0, stream>>>(csum, nch, coff, row_ptr, N, E);
    k_scan_final<<<nch, 256, 0, stream>>>(degc, N, coff, row_ptr, fill, dis);
    k_fill<<<CDIV(E, 256), 256, 0, stream>>>(src, dst, E, row_ptr, fill, esrc);

    const int ggrid = CDIV(N, 64) * 2;

    // layer 1
    k_agg<128, true><<<CDIV(N * 64, 256), 256, 0, stream>>>(x, Xhi, dis, row_ptr, esrc, N, Ahi);
    k_gemm_bf16<128, false><<<ggrid, 256, 0, stream>>>(Ahi, W1hi, b1, N, Hhi,
                                                       batch, sumbuf, maxbuf);
    // layer 2
    k_agg<256, false><<<CDIV(N * 64, 256), 256, 0, stream>>>(nullptr, Hhi, dis, row_ptr,
                                                             esrc, N, Ahi);
    k_gemm_bf16<256, false><<<ggrid, 256, 0, stream>>>(Ahi, W2hi, b2, N, Hhi,
                                                       batch, sumbuf, maxbuf);
    // layer 3 + fused pooling
    k_agg<256, false><<<CDIV(N * 64, 256), 256, 0, stream>>>(nullptr, Hhi, dis, row_ptr,
                                                             esrc, N, Ahi);
    k_gemm_bf16<256, true><<<ggrid, 256, 0, stream>>>(Ahi, W3hi, b3, N, Hhi,
                                                      batch, sumbuf, maxbuf);

    // fused pool finalize + MLP head
    k_head<<<G, 512, 0, stream>>>(sumbuf, maxbuf, batch, N, Wc1, bc1, Wc2, bc2, Wc3, bc3, out);
}